// Round 9
// baseline (183.587 us; speedup 1.0000x reference)
//
#include <hip/hip_runtime.h>
#include <math.h>

#define B_  2048
#define N_  4096
#define D_  1024
#define NEGG 4093   // negatives per group = N - 2 - K (K=1)

typedef _Float16 f16;
typedef unsigned long long u64;
typedef __attribute__((ext_vector_type(8))) _Float16 f16x8;
typedef __attribute__((ext_vector_type(4))) float     f32x4;

#define AS1 __attribute__((address_space(1)))
#define AS3 __attribute__((address_space(3)))

__device__ __forceinline__ void gload_lds16(const void* g, void* l) {
    __builtin_amdgcn_global_load_lds((const AS1 void*)g, (AS3 void*)l, 16, 0, 0);
}

// ---------------------------------------------------------------------------
// Kernel 0: split h=[h_i;h_j] (fp32) into fp16 hi/lo pair: h = hi + lo + O(2^-22)
// ---------------------------------------------------------------------------
struct alignas(8) h4 { f16 a, b, c, d; };

__global__ __launch_bounds__(256)
void split_kernel(const float* __restrict__ a, const float* __restrict__ b,
                  f16* __restrict__ ph, f16* __restrict__ pl)
{
    size_t t   = (size_t)blockIdx.x * 256 + threadIdx.x;
    size_t off = t * 4;                       // 4 floats per thread
    const size_t half = (size_t)B_ * D_;
    const float* src = (off < half) ? (a + off) : (b + (off - half));
    float4 v = *reinterpret_cast<const float4*>(src);
    f16 h0 = (f16)v.x, h1 = (f16)v.y, h2 = (f16)v.z, h3 = (f16)v.w;
    f16 l0 = (f16)(v.x - (float)h0);
    f16 l1 = (f16)(v.y - (float)h1);
    f16 l2 = (f16)(v.z - (float)h2);
    f16 l3 = (f16)(v.w - (float)h3);
    *reinterpret_cast<h4*>(ph + off) = {h0, h1, h2, h3};
    *reinterpret_cast<h4*>(pl + off) = {l0, l1, l2, l3};
}

// ---------------------------------------------------------------------------
// Kernel 1: sim = 2*(Hh Hh^T + Hh Hl^T + Hl Hh^T) via MFMA 16x16x32 f16.
// 496 strict-lower-tri 128x128 tiles; diag subtiles dealt s%31 across their
// 31 holder blocks; float4-transpose mirrors; XOR-swizzled LDS. (round-4 exact)
// ---------------------------------------------------------------------------
__global__ __launch_bounds__(256)
void gemm_kernel(const f16* __restrict__ Hh, const f16* __restrict__ Hl,
                 float* __restrict__ sim)
{
    __shared__ __align__(16) f16 lds[4][128 * 32];
    const int tid  = threadIdx.x;
    const int wave = tid >> 6;
    const int lane = tid & 63;

    int idx = blockIdx.x;
    int by = (int)((sqrtf(8.0f * (float)idx + 1.0f) + 1.0f) * 0.5f);
    while (by * (by - 1) / 2 > idx) --by;
    while ((by + 1) * by / 2 <= idx) ++by;
    int bx = idx - by * (by - 1) / 2;
    const int m0 = by * 128;
    const int n0 = bx * 128;

    int xs = -1, xpanel = 0, xb = 0;
    {
        int cnt = 0;
        for (int s = bx; s < 36; s += 31, ++cnt)
            if (cnt == wave) { xs = s; xpanel = 0; xb = by; }
        for (int s = by - 1; s < 36; s += 31, ++cnt)
            if (cnt == wave) { xs = s; xpanel = 2; xb = bx; }
    }
    int xmt = 0, xnt = 0;
    if (xs >= 0) {
        while ((xmt + 1) * (xmt + 2) / 2 <= xs) ++xmt;
        xnt = xs - xmt * (xmt + 1) / 2;
    }

    const int wm = (wave >> 1) * 64;
    const int wn = (wave & 1) * 64;
    const int l15  = lane & 15;
    const int quad = lane >> 4;

    f32x4 acc[4][4];
#pragma unroll
    for (int i = 0; i < 4; i++)
#pragma unroll
        for (int j = 0; j < 4; j++) { acc[i][j][0]=0.f; acc[i][j][1]=0.f; acc[i][j][2]=0.f; acc[i][j][3]=0.f; }
    f32x4 xacc; xacc[0]=0.f; xacc[1]=0.f; xacc[2]=0.f; xacc[3]=0.f;

    const int lr = lane >> 2;
    const int sw_st = (lr ^ (lr >> 2)) & 3;
    const f16* gsrc = ((wave & 1) ? Hl : Hh)
                    + (size_t)((wave & 2) ? n0 : m0) * D_
                    + (size_t)lr * D_ + (size_t)(((lane & 3) ^ sw_st) * 8);

    const int sw_rd = (l15 ^ (l15 >> 2)) & 3;

    for (int k0 = 0; k0 < D_; k0 += 32) {
#pragma unroll
        for (int s = 0; s < 8; ++s) {
            const f16* gp = gsrc + (size_t)(s * 16) * D_ + k0;
            gload_lds16(gp, &lds[wave][s * 512]);
        }
        __syncthreads();

        f16x8 ah[4], al[4], bh[4], bl[4];
        const int qc = ((quad ^ sw_rd) & 3) * 8;
#pragma unroll
        for (int mt = 0; mt < 4; ++mt) {
            int row = wm + mt * 16 + l15;
            ah[mt] = *reinterpret_cast<const f16x8*>(&lds[0][row * 32 + qc]);
            al[mt] = *reinterpret_cast<const f16x8*>(&lds[1][row * 32 + qc]);
        }
#pragma unroll
        for (int nt = 0; nt < 4; ++nt) {
            int row = wn + nt * 16 + l15;
            bh[nt] = *reinterpret_cast<const f16x8*>(&lds[2][row * 32 + qc]);
            bl[nt] = *reinterpret_cast<const f16x8*>(&lds[3][row * 32 + qc]);
        }
#pragma unroll
        for (int mt = 0; mt < 4; ++mt)
#pragma unroll
            for (int nt = 0; nt < 4; ++nt) {
                acc[mt][nt] = __builtin_amdgcn_mfma_f32_16x16x32_f16(ah[mt], bh[nt], acc[mt][nt], 0, 0, 0);
                acc[mt][nt] = __builtin_amdgcn_mfma_f32_16x16x32_f16(ah[mt], bl[nt], acc[mt][nt], 0, 0, 0);
                acc[mt][nt] = __builtin_amdgcn_mfma_f32_16x16x32_f16(al[mt], bh[nt], acc[mt][nt], 0, 0, 0);
            }
        if (xs >= 0) {
            f16x8 xah = *reinterpret_cast<const f16x8*>(&lds[xpanel    ][(xmt * 16 + l15) * 32 + qc]);
            f16x8 xal = *reinterpret_cast<const f16x8*>(&lds[xpanel + 1][(xmt * 16 + l15) * 32 + qc]);
            f16x8 xbh = *reinterpret_cast<const f16x8*>(&lds[xpanel    ][(xnt * 16 + l15) * 32 + qc]);
            f16x8 xbl = *reinterpret_cast<const f16x8*>(&lds[xpanel + 1][(xnt * 16 + l15) * 32 + qc]);
            xacc = __builtin_amdgcn_mfma_f32_16x16x32_f16(xah, xbh, xacc, 0, 0, 0);
            xacc = __builtin_amdgcn_mfma_f32_16x16x32_f16(xah, xbl, xacc, 0, 0, 0);
            xacc = __builtin_amdgcn_mfma_f32_16x16x32_f16(xal, xbh, xacc, 0, 0, 0);
        }
        __syncthreads();
    }

#pragma unroll
    for (int mt = 0; mt < 4; ++mt) {
        int r = m0 + wm + mt * 16 + quad * 4;
#pragma unroll
        for (int nt = 0; nt < 4; ++nt) {
            int c = n0 + wn + nt * 16 + l15;
#pragma unroll
            for (int reg = 0; reg < 4; ++reg)
                sim[(size_t)(r + reg) * N_ + c] = 2.0f * acc[mt][nt][reg];
        }
    }
#pragma unroll
    for (int mt = 0; mt < 4; ++mt) {
        int cb = m0 + wm + mt * 16 + quad * 4;
#pragma unroll
        for (int nt = 0; nt < 4; ++nt) {
            int rr = n0 + wn + nt * 16 + l15;
            float4 v = { 2.0f * acc[mt][nt][0], 2.0f * acc[mt][nt][1],
                         2.0f * acc[mt][nt][2], 2.0f * acc[mt][nt][3] };
            *reinterpret_cast<float4*>(&sim[(size_t)rr * N_ + cb]) = v;
        }
    }
    if (xs >= 0) {
        int rb = xb * 128 + xmt * 16 + quad * 4;
        int cc = xb * 128 + xnt * 16 + l15;
#pragma unroll
        for (int reg = 0; reg < 4; ++reg)
            sim[(size_t)(rb + reg) * N_ + cc] = 2.0f * xacc[reg];
        if (xmt != xnt) {
            int rr = xb * 128 + xnt * 16 + l15;
            int cb = xb * 128 + xmt * 16 + quad * 4;
            float4 v = { 2.0f * xacc[0], 2.0f * xacc[1], 2.0f * xacc[2], 2.0f * xacc[3] };
            *reinterpret_cast<float4*>(&sim[(size_t)rr * N_ + cb]) = v;
        }
    }
}

// ---------------------------------------------------------------------------
// Kernel 2: branch-free top-4, 4 consecutive anchors per block (512 blocks).
// u64 key (mono(val)<<32)|(4095-j) == jax.lax.top_k stable order.
// ---------------------------------------------------------------------------
__device__ __forceinline__ u64 mkkey(float v, int j) {
    unsigned u = __float_as_uint(v);
    u = (u & 0x80000000u) ? ~u : (u | 0x80000000u);   // monotonic float map
    return ((u64)u << 32) | (unsigned)(4095 - j);
}

__device__ __forceinline__ void kins(u64& k0, u64& k1, u64& k2, u64& k3, u64 key) {
    u64 lo = key, t;
    t = (k0 > lo) ? k0 : lo; lo = (k0 > lo) ? lo : k0; k0 = t;
    t = (k1 > lo) ? k1 : lo; lo = (k1 > lo) ? lo : k1; k1 = t;
    t = (k2 > lo) ? k2 : lo; lo = (k2 > lo) ? lo : k2; k2 = t;
    k3 = (k3 > lo) ? k3 : lo;
}

__global__ __launch_bounds__(256)
void topk_kernel(const float* __restrict__ sim, int* __restrict__ e,
                 int* __restrict__ ex)
{
    const int tid = threadIdx.x;
    __shared__ u64 lk[1024];

    for (int a = 0; a < 4; ++a) {
        const int i = blockIdx.x * 4 + a;               // anchor
        const float* rowA = sim + (size_t)i * N_ + B_;  // sim[i, B+j]
        const float* rowB = sim + (size_t)(B_ + i) * N_;// sim[B+i, j]

        u64 k0 = 0, k1 = 0, k2 = 0, k3 = 0;             // 0 < every real key
#pragma unroll
        for (int it = 0; it < 4; ++it) {
            int base = tid * 4 + it * 1024;
            float4 v4 = (base < B_) ? *reinterpret_cast<const float4*>(rowA + base)
                                    : *reinterpret_cast<const float4*>(rowB + (base - B_));
            float vals[4] = { v4.x, v4.y, v4.z, v4.w };
#pragma unroll
            for (int u = 0; u < 4; ++u)
                kins(k0, k1, k2, k3, mkkey(vals[u], base + u));
        }

        __syncthreads();                                // protect lk reuse
        lk[tid * 4 + 0] = k0; lk[tid * 4 + 1] = k1;
        lk[tid * 4 + 2] = k2; lk[tid * 4 + 3] = k3;
        __syncthreads();

        if (tid < 64) {
#pragma unroll
            for (int w = 1; w < 4; ++w) {
                int th = tid + w * 64;
#pragma unroll
                for (int s = 0; s < 4; ++s)
                    kins(k0, k1, k2, k3, lk[th * 4 + s]);
            }
            u64 M[4];
#pragma unroll
            for (int r = 0; r < 4; ++r) {
                u64 mx = k0;
#pragma unroll
                for (int off = 32; off >= 1; off >>= 1) {
                    u64 o = __shfl_xor(mx, off);
                    mx = (mx > o) ? mx : o;
                }
                M[r] = mx;
                if (k0 == mx) { k0 = k1; k1 = k2; k2 = k3; k3 = 0; }  // keys unique
            }
            if (tid == 0) {
                int topi[4];
#pragma unroll
                for (int r = 0; r < 4; ++r)
                    topi[r] = 4095 - (int)(unsigned)(M[r] & 0xFFFFFFFFull);
                int exi[2] = {0x7fffffff, 0x7fffffff}; int ei = 0;
                int exb[2] = {0x7fffffff, 0x7fffffff}; int eb = 0;
                int taken = 0;
#pragma unroll
                for (int t = 0; t < 4; ++t) {
                    if (taken >= 2) break;
                    int idxj = topi[t];
                    if (idxj == i || idxj == i + B_) continue;   // anchor pair
                    ++taken;
                    if (idxj < B_) exi[ei++] = B_ + idxj;        // row i, col B+idx
                    else           exb[eb++] = idxj - B_;        // row B+i, col idx-B
                }
                if (ei == 2 && exi[0] > exi[1]) { int t = exi[0]; exi[0] = exi[1]; exi[1] = t; }
                if (eb == 2 && exb[0] > exb[1]) { int t = exb[0]; exb[0] = exb[1]; exb[1] = t; }
                e[i] = ei;        ex[2*i]        = exi[0]; ex[2*i+1]        = exi[1];
                e[B_ + i] = eb;   ex[2*(B_+i)]   = exb[0]; ex[2*(B_+i)+1]   = exb[1];
            }
        }
    }
}

// ---------------------------------------------------------------------------
// Kernel 3: exclusive prefix sum E[r] of e[r], E[4096] = total.
// ---------------------------------------------------------------------------
__global__ __launch_bounds__(256)
void scan_kernel(const int* __restrict__ e, int* __restrict__ E)
{
    __shared__ int partial[256];
    const int tid = threadIdx.x;
    const int base = tid * 16;
    int loc[16];
    int s = 0;
#pragma unroll
    for (int q = 0; q < 16; q++) { loc[q] = s; s += e[base + q]; }
    partial[tid] = s;
    __syncthreads();
    for (int off = 1; off < 256; off <<= 1) {
        int tmp = (tid >= off) ? partial[tid - off] : 0;
        __syncthreads();
        partial[tid] += tmp;
        __syncthreads();
    }
    int excl = partial[tid] - s;
#pragma unroll
    for (int q = 0; q < 16; q++) E[base + q] = excl + loc[q];
    if (tid == 255) E[4096] = partial[255];
}

// ---------------------------------------------------------------------------
// Kernel 4: per-group online-LSE, 8 consecutive groups per block (512 blocks):
// E->LDS once per block; setup on 24 parallel lanes at LDS latency; round-6
// online rare-branch main loop; shfl butterfly reduce; one atomicAdd/block.
// ---------------------------------------------------------------------------
__global__ __launch_bounds__(256)
void group_kernel(const float* __restrict__ sim, const int* __restrict__ ex,
                  const int* __restrict__ E, float* __restrict__ out)
{
    const int tid = threadIdx.x;
    const int g0  = blockIdx.x * 8;
    __shared__ int   sE[4097];
    __shared__ float posv[8][2];
    __shared__ int   pR[8][3], pCa[8][3], pCb[8][3], pX[8][3][4], nP[8];
    __shared__ float wm4[4], ws4[4];

    // ---- copy E -> LDS ----
    {
        const int b = tid * 16;
#pragma unroll
        for (int q = 0; q < 16; q += 4) {
            int4 v = *reinterpret_cast<const int4*>(E + b + q);
            sE[b+q] = v.x; sE[b+q+1] = v.y; sE[b+q+2] = v.z; sE[b+q+3] = v.w;
        }
        if (tid == 0) sE[4096] = E[4096];
    }
    __syncthreads();

    // ---- parallel setup: 24 lanes, gi = lane/3, role = lane%3 ----
    if (tid < 24) {
        const int gi = tid / 3, role = tid % 3;
        const int g = g0 + gi;
        if (role < 2) {
            int p = 2 * g + role;
            int lo = 0, hi = N_ - 1;
            while (lo < hi) {
                int mid = (lo + hi + 1) >> 1;
                if (mid + sE[mid] <= p) lo = mid; else hi = mid - 1;
            }
            int r = lo;
            int q = p - (r + sE[r]);
            int pr = (r < B_) ? r + B_ : r - B_;
            int a0 = ex[2*r], a1 = ex[2*r+1];
            int p0 = pr, p1 = a0, p2 = a1;               // sort3 (sentinels last)
            if (p0 > p1) { int tm = p0; p0 = p1; p1 = tm; }
            if (p1 > p2) { int tm = p1; p1 = p2; p2 = tm; }
            if (p0 > p1) { int tm = p0; p0 = p1; p1 = tm; }
            int c = (q == 0) ? p0 : ((q == 1) ? p1 : p2);
            posv[gi][role] = sim[(size_t)r * N_ + c];
        } else {
            long long s0 = (long long)NEGG * g;
            long long s1 = s0 + NEGG;
            int lo = 0, hi = N_ - 1;
            while (lo < hi) {
                int mid = (lo + hi + 1) >> 1;
                long long Q = 4094LL * mid - sE[mid];
                if (Q <= s0) lo = mid; else hi = mid - 1;
            }
            int np = 0;
            long long s = s0;
            int r = lo;
            while (s < s1 && np < 3) {
                long long Qr = 4094LL * r - sE[r];
                int er = sE[r+1] - sE[r];
                int nr = 4094 - er;
                long long ka = s - Qr;
                long long kb = s1 - Qr; if (kb > nr) kb = nr;
                int X[4];
                X[0] = (r < B_) ? r : r - B_;
                X[1] = (r < B_) ? r + B_ : r;
                X[2] = ex[2*r]; X[3] = ex[2*r+1];
                if (X[0] > X[1]) { int t = X[0]; X[0] = X[1]; X[1] = t; }
                if (X[2] > X[3]) { int t = X[2]; X[2] = X[3]; X[3] = t; }
                if (X[0] > X[2]) { int t = X[0]; X[0] = X[2]; X[2] = t; }
                if (X[1] > X[3]) { int t = X[1]; X[1] = X[3]; X[3] = t; }
                if (X[1] > X[2]) { int t = X[1]; X[1] = X[2]; X[2] = t; }
                int ca = (int)ka;
#pragma unroll
                for (int t = 0; t < 4; t++) if (X[t] <= ca) ca++;
                int cb = (int)kb - 1;
#pragma unroll
                for (int t = 0; t < 4; t++) if (X[t] <= cb) cb++;
                cb += 1;
                pR[gi][np] = r; pCa[gi][np] = ca; pCb[gi][np] = cb;
#pragma unroll
                for (int t = 0; t < 4; t++) pX[gi][np][t] = X[t];
                ++np;
                s += (kb - ka);
                r += 1;
            }
            nP[gi] = np;
        }
    }
    __syncthreads();

    float gacc = 0.f;
    for (int gi = 0; gi < 8; ++gi) {
        float m = -3.0e38f, sacc = 0.f;
        const int np = nP[gi];
        for (int pz = 0; pz < np; ++pz) {
            const int r = pR[gi][pz], ca = pCa[gi][pz], cb = pCb[gi][pz];
            const int X0 = pX[gi][pz][0], X1 = pX[gi][pz][1];
            const int X2 = pX[gi][pz][2], X3 = pX[gi][pz][3];
            const float* row = sim + (size_t)r * N_;
            const int start = ca & ~3;
            for (int c4 = start + tid * 4; c4 < cb; c4 += 1024) {
                float4 v4 = *reinterpret_cast<const float4*>(row + c4);
                float vals[4] = { v4.x, v4.y, v4.z, v4.w };
#pragma unroll
                for (int u = 0; u < 4; ++u) {
                    int c = c4 + u;
                    bool keep = (c >= ca) & (c < cb) &
                                (c != X0) & (c != X1) & (c != X2) & (c != X3);
                    float val = keep ? vals[u] : -INFINITY;
                    if (val <= m) {
                        sacc += __expf(val - m);          // exp(-inf)=0
                    } else {
                        sacc = sacc * __expf(m - val) + 1.0f;
                        m = val;
                    }
                }
            }
        }
        // wave butterfly reduce (m, sacc)
#pragma unroll
        for (int off = 32; off >= 1; off >>= 1) {
            float m2 = __shfl_xor(m, off);
            float s2 = __shfl_xor(sacc, off);
            float nm = fmaxf(m, m2);
            sacc = sacc * __expf(m - nm) + s2 * __expf(m2 - nm);
            m = nm;
        }
        if ((tid & 63) == 0) { wm4[tid >> 6] = m; ws4[tid >> 6] = sacc; }
        __syncthreads();
        if (tid == 0) {
            float mm = wm4[0], ss = ws4[0];
#pragma unroll
            for (int w = 1; w < 4; ++w) {
                float nm = fmaxf(mm, wm4[w]);
                ss = ss * __expf(mm - nm) + ws4[w] * __expf(wm4[w] - nm);
                mm = nm;
            }
            float q0 = posv[gi][0], q1 = posv[gi][1];
            float nm = fmaxf(mm, fmaxf(q0, q1));
            float stot = ss * __expf(mm - nm) + __expf(q0 - nm) + __expf(q1 - nm);
            gacc += (nm + __logf(stot)) - q0;
        }
        __syncthreads();   // protect wm4/ws4 reuse for next group
    }
    if (tid == 0) atomicAdd(out, gacc * (1.0f / 4096.0f));
}

// ---------------------------------------------------------------------------
extern "C" void kernel_launch(void* const* d_in, const int* in_sizes, int n_in,
                              void* d_out, int out_size, void* d_ws, size_t ws_size,
                              hipStream_t stream)
{
    const float* hi = (const float*)d_in[0];
    const float* hj = (const float*)d_in[1];
    char* ws = (char*)d_ws;
    size_t off = 0;
    float* sim = (float*)(ws + off); off += (size_t)N_ * N_ * sizeof(float);  // 64 MB
    f16*   Hh  = (f16*)(ws + off);   off += (size_t)N_ * D_ * sizeof(f16);    // 8 MB
    f16*   Hl  = (f16*)(ws + off);   off += (size_t)N_ * D_ * sizeof(f16);    // 8 MB
    int*   e   = (int*)(ws + off);   off += 4096 * sizeof(int);
    int*   ex  = (int*)(ws + off);   off += 8192 * sizeof(int);
    int*   E   = (int*)(ws + off);   off += 4100 * sizeof(int);

    hipMemsetAsync(d_out, 0, sizeof(float), stream);       // zero atomic target
    split_kernel<<<(N_ * D_ / 4 + 255) / 256, 256, 0, stream>>>(hi, hj, Hh, Hl);
    const int nblocks = (N_ / 128) * (N_ / 128 - 1) / 2;   // 496 strict lower-tri
    gemm_kernel<<<nblocks, 256, 0, stream>>>(Hh, Hl, sim);
    topk_kernel<<<B_ / 4, 256, 0, stream>>>(sim, e, ex);
    scan_kernel<<<1, 256, 0, stream>>>(e, E);
    group_kernel<<<N_ / 8, 256, 0, stream>>>(sim, ex, E, (float*)d_out);
}

// Round 10
// 173.485 us; speedup vs baseline: 1.0582x; 1.0582x over previous
//
#include <hip/hip_runtime.h>
#include <math.h>

#define B_  2048
#define N_  4096
#define D_  1024
#define NEGG 4093   // negatives per group = N - 2 - K (K=1)

typedef _Float16 f16;
typedef unsigned long long u64;
typedef __attribute__((ext_vector_type(8))) _Float16 f16x8;
typedef __attribute__((ext_vector_type(4))) float     f32x4;

#define AS1 __attribute__((address_space(1)))
#define AS3 __attribute__((address_space(3)))

__device__ __forceinline__ void gload_lds16(const void* g, void* l) {
    __builtin_amdgcn_global_load_lds((const AS1 void*)g, (AS3 void*)l, 16, 0, 0);
}

// ---------------------------------------------------------------------------
// Kernel 0: split h=[h_i;h_j] (fp32) into fp16 hi/lo pair: h = hi + lo + O(2^-22)
// ---------------------------------------------------------------------------
struct alignas(8) h4 { f16 a, b, c, d; };

__global__ __launch_bounds__(256)
void split_kernel(const float* __restrict__ a, const float* __restrict__ b,
                  f16* __restrict__ ph, f16* __restrict__ pl)
{
    size_t t   = (size_t)blockIdx.x * 256 + threadIdx.x;
    size_t off = t * 4;                       // 4 floats per thread
    const size_t half = (size_t)B_ * D_;
    const float* src = (off < half) ? (a + off) : (b + (off - half));
    float4 v = *reinterpret_cast<const float4*>(src);
    f16 h0 = (f16)v.x, h1 = (f16)v.y, h2 = (f16)v.z, h3 = (f16)v.w;
    f16 l0 = (f16)(v.x - (float)h0);
    f16 l1 = (f16)(v.y - (float)h1);
    f16 l2 = (f16)(v.z - (float)h2);
    f16 l3 = (f16)(v.w - (float)h3);
    *reinterpret_cast<h4*>(ph + off) = {h0, h1, h2, h3};
    *reinterpret_cast<h4*>(pl + off) = {l0, l1, l2, l3};
}

// ---------------------------------------------------------------------------
// Kernel 1: sim = 2*(Hh Hh^T + Hh Hl^T + Hl Hh^T) via MFMA 16x16x32 f16.
// 496 strict-lower-tri 128x128 tiles; diag subtiles dealt s%31 across their
// 31 holder blocks; float4-transpose mirrors; XOR-swizzled LDS. (round-4 exact)
// ---------------------------------------------------------------------------
__global__ __launch_bounds__(256)
void gemm_kernel(const f16* __restrict__ Hh, const f16* __restrict__ Hl,
                 float* __restrict__ sim)
{
    __shared__ __align__(16) f16 lds[4][128 * 32];
    const int tid  = threadIdx.x;
    const int wave = tid >> 6;
    const int lane = tid & 63;

    int idx = blockIdx.x;
    int by = (int)((sqrtf(8.0f * (float)idx + 1.0f) + 1.0f) * 0.5f);
    while (by * (by - 1) / 2 > idx) --by;
    while ((by + 1) * by / 2 <= idx) ++by;
    int bx = idx - by * (by - 1) / 2;
    const int m0 = by * 128;
    const int n0 = bx * 128;

    int xs = -1, xpanel = 0, xb = 0;
    {
        int cnt = 0;
        for (int s = bx; s < 36; s += 31, ++cnt)
            if (cnt == wave) { xs = s; xpanel = 0; xb = by; }
        for (int s = by - 1; s < 36; s += 31, ++cnt)
            if (cnt == wave) { xs = s; xpanel = 2; xb = bx; }
    }
    int xmt = 0, xnt = 0;
    if (xs >= 0) {
        while ((xmt + 1) * (xmt + 2) / 2 <= xs) ++xmt;
        xnt = xs - xmt * (xmt + 1) / 2;
    }

    const int wm = (wave >> 1) * 64;
    const int wn = (wave & 1) * 64;
    const int l15  = lane & 15;
    const int quad = lane >> 4;

    f32x4 acc[4][4];
#pragma unroll
    for (int i = 0; i < 4; i++)
#pragma unroll
        for (int j = 0; j < 4; j++) { acc[i][j][0]=0.f; acc[i][j][1]=0.f; acc[i][j][2]=0.f; acc[i][j][3]=0.f; }
    f32x4 xacc; xacc[0]=0.f; xacc[1]=0.f; xacc[2]=0.f; xacc[3]=0.f;

    const int lr = lane >> 2;
    const int sw_st = (lr ^ (lr >> 2)) & 3;
    const f16* gsrc = ((wave & 1) ? Hl : Hh)
                    + (size_t)((wave & 2) ? n0 : m0) * D_
                    + (size_t)lr * D_ + (size_t)(((lane & 3) ^ sw_st) * 8);

    const int sw_rd = (l15 ^ (l15 >> 2)) & 3;

    for (int k0 = 0; k0 < D_; k0 += 32) {
#pragma unroll
        for (int s = 0; s < 8; ++s) {
            const f16* gp = gsrc + (size_t)(s * 16) * D_ + k0;
            gload_lds16(gp, &lds[wave][s * 512]);
        }
        __syncthreads();

        f16x8 ah[4], al[4], bh[4], bl[4];
        const int qc = ((quad ^ sw_rd) & 3) * 8;
#pragma unroll
        for (int mt = 0; mt < 4; ++mt) {
            int row = wm + mt * 16 + l15;
            ah[mt] = *reinterpret_cast<const f16x8*>(&lds[0][row * 32 + qc]);
            al[mt] = *reinterpret_cast<const f16x8*>(&lds[1][row * 32 + qc]);
        }
#pragma unroll
        for (int nt = 0; nt < 4; ++nt) {
            int row = wn + nt * 16 + l15;
            bh[nt] = *reinterpret_cast<const f16x8*>(&lds[2][row * 32 + qc]);
            bl[nt] = *reinterpret_cast<const f16x8*>(&lds[3][row * 32 + qc]);
        }
#pragma unroll
        for (int mt = 0; mt < 4; ++mt)
#pragma unroll
            for (int nt = 0; nt < 4; ++nt) {
                acc[mt][nt] = __builtin_amdgcn_mfma_f32_16x16x32_f16(ah[mt], bh[nt], acc[mt][nt], 0, 0, 0);
                acc[mt][nt] = __builtin_amdgcn_mfma_f32_16x16x32_f16(ah[mt], bl[nt], acc[mt][nt], 0, 0, 0);
                acc[mt][nt] = __builtin_amdgcn_mfma_f32_16x16x32_f16(al[mt], bh[nt], acc[mt][nt], 0, 0, 0);
            }
        if (xs >= 0) {
            f16x8 xah = *reinterpret_cast<const f16x8*>(&lds[xpanel    ][(xmt * 16 + l15) * 32 + qc]);
            f16x8 xal = *reinterpret_cast<const f16x8*>(&lds[xpanel + 1][(xmt * 16 + l15) * 32 + qc]);
            f16x8 xbh = *reinterpret_cast<const f16x8*>(&lds[xpanel    ][(xnt * 16 + l15) * 32 + qc]);
            f16x8 xbl = *reinterpret_cast<const f16x8*>(&lds[xpanel + 1][(xnt * 16 + l15) * 32 + qc]);
            xacc = __builtin_amdgcn_mfma_f32_16x16x32_f16(xah, xbh, xacc, 0, 0, 0);
            xacc = __builtin_amdgcn_mfma_f32_16x16x32_f16(xah, xbl, xacc, 0, 0, 0);
            xacc = __builtin_amdgcn_mfma_f32_16x16x32_f16(xal, xbh, xacc, 0, 0, 0);
        }
        __syncthreads();
    }

#pragma unroll
    for (int mt = 0; mt < 4; ++mt) {
        int r = m0 + wm + mt * 16 + quad * 4;
#pragma unroll
        for (int nt = 0; nt < 4; ++nt) {
            int c = n0 + wn + nt * 16 + l15;
#pragma unroll
            for (int reg = 0; reg < 4; ++reg)
                sim[(size_t)(r + reg) * N_ + c] = 2.0f * acc[mt][nt][reg];
        }
    }
#pragma unroll
    for (int mt = 0; mt < 4; ++mt) {
        int cb = m0 + wm + mt * 16 + quad * 4;
#pragma unroll
        for (int nt = 0; nt < 4; ++nt) {
            int rr = n0 + wn + nt * 16 + l15;
            float4 v = { 2.0f * acc[mt][nt][0], 2.0f * acc[mt][nt][1],
                         2.0f * acc[mt][nt][2], 2.0f * acc[mt][nt][3] };
            *reinterpret_cast<float4*>(&sim[(size_t)rr * N_ + cb]) = v;
        }
    }
    if (xs >= 0) {
        int rb = xb * 128 + xmt * 16 + quad * 4;
        int cc = xb * 128 + xnt * 16 + l15;
#pragma unroll
        for (int reg = 0; reg < 4; ++reg)
            sim[(size_t)(rb + reg) * N_ + cc] = 2.0f * xacc[reg];
        if (xmt != xnt) {
            int rr = xb * 128 + xnt * 16 + l15;
            int cb = xb * 128 + xmt * 16 + quad * 4;
            float4 v = { 2.0f * xacc[0], 2.0f * xacc[1], 2.0f * xacc[2], 2.0f * xacc[3] };
            *reinterpret_cast<float4*>(&sim[(size_t)rr * N_ + cb]) = v;
        }
    }
}

// ---------------------------------------------------------------------------
// Kernel 2: per-anchor top-4, BRANCH-FREE (round-8 exact: 2048 blocks).
// u64 key (mono(val)<<32)|(4095-j) == jax.lax.top_k stable order.
// ---------------------------------------------------------------------------
__device__ __forceinline__ u64 mkkey(float v, int j) {
    unsigned u = __float_as_uint(v);
    u = (u & 0x80000000u) ? ~u : (u | 0x80000000u);   // monotonic float map
    return ((u64)u << 32) | (unsigned)(4095 - j);
}

__device__ __forceinline__ void kins(u64& k0, u64& k1, u64& k2, u64& k3, u64 key) {
    u64 lo = key, t;
    t = (k0 > lo) ? k0 : lo; lo = (k0 > lo) ? lo : k0; k0 = t;
    t = (k1 > lo) ? k1 : lo; lo = (k1 > lo) ? lo : k1; k1 = t;
    t = (k2 > lo) ? k2 : lo; lo = (k2 > lo) ? lo : k2; k2 = t;
    k3 = (k3 > lo) ? k3 : lo;
}

__global__ __launch_bounds__(256)
void topk_kernel(const float* __restrict__ sim, int* __restrict__ e,
                 int* __restrict__ ex)
{
    const int i   = blockIdx.x;      // anchor
    const int tid = threadIdx.x;
    const float* rowA = sim + (size_t)i * N_ + B_;        // sim[i, B+j]
    const float* rowB = sim + (size_t)(B_ + i) * N_;      // sim[B+i, j]

    u64 k0 = 0, k1 = 0, k2 = 0, k3 = 0;   // 0 < every real key
#pragma unroll
    for (int it = 0; it < 4; ++it) {
        int base = tid * 4 + it * 1024;
        float4 v4 = (base < B_) ? *reinterpret_cast<const float4*>(rowA + base)
                                : *reinterpret_cast<const float4*>(rowB + (base - B_));
        float vals[4] = { v4.x, v4.y, v4.z, v4.w };
#pragma unroll
        for (int u = 0; u < 4; ++u)
            kins(k0, k1, k2, k3, mkkey(vals[u], base + u));
    }

    __shared__ u64 lk[1024];
    lk[tid * 4 + 0] = k0; lk[tid * 4 + 1] = k1;
    lk[tid * 4 + 2] = k2; lk[tid * 4 + 3] = k3;
    __syncthreads();

    if (tid < 64) {
#pragma unroll
        for (int w = 1; w < 4; ++w) {
            int th = tid + w * 64;
#pragma unroll
            for (int s = 0; s < 4; ++s)
                kins(k0, k1, k2, k3, lk[th * 4 + s]);
        }
        u64 M[4];
#pragma unroll
        for (int r = 0; r < 4; ++r) {
            u64 mx = k0;
#pragma unroll
            for (int off = 32; off >= 1; off >>= 1) {
                u64 o = __shfl_xor(mx, off);
                mx = (mx > o) ? mx : o;
            }
            M[r] = mx;
            if (k0 == mx) { k0 = k1; k1 = k2; k2 = k3; k3 = 0; }  // keys unique
        }
        if (tid == 0) {
            int topi[4];
#pragma unroll
            for (int r = 0; r < 4; ++r)
                topi[r] = 4095 - (int)(unsigned)(M[r] & 0xFFFFFFFFull);
            int exi[2] = {0x7fffffff, 0x7fffffff}; int ei = 0;
            int exb[2] = {0x7fffffff, 0x7fffffff}; int eb = 0;
            int taken = 0;
#pragma unroll
            for (int t = 0; t < 4; ++t) {
                if (taken >= 2) break;
                int idxj = topi[t];
                if (idxj == i || idxj == i + B_) continue;   // anchor pair: invalid
                ++taken;
                if (idxj < B_) exi[ei++] = B_ + idxj;        // row i, col B+idx
                else           exb[eb++] = idxj - B_;        // row B+i, col idx-B
            }
            if (ei == 2 && exi[0] > exi[1]) { int t = exi[0]; exi[0] = exi[1]; exi[1] = t; }
            if (eb == 2 && exb[0] > exb[1]) { int t = exb[0]; exb[0] = exb[1]; exb[1] = t; }
            e[i] = ei;        ex[2*i]        = exi[0]; ex[2*i+1]        = exi[1];
            e[B_ + i] = eb;   ex[2*(B_+i)]   = exb[0]; ex[2*(B_+i)+1]   = exb[1];
        }
    }
}

// ---------------------------------------------------------------------------
// Kernel 3: exclusive prefix sum E[r] of e[r]; also zeroes out[0] (replaces
// the hipMemsetAsync dispatch — same-stream kernel boundary gives visibility).
// ---------------------------------------------------------------------------
__global__ __launch_bounds__(256)
void scan_kernel(const int* __restrict__ e, int* __restrict__ E,
                 float* __restrict__ out)
{
    __shared__ int partial[256];
    const int tid = threadIdx.x;
    if (tid == 0) out[0] = 0.0f;
    const int base = tid * 16;
    int loc[16];
    int s = 0;
#pragma unroll
    for (int q = 0; q < 16; q++) { loc[q] = s; s += e[base + q]; }
    partial[tid] = s;
    __syncthreads();
    for (int off = 1; off < 256; off <<= 1) {
        int tmp = (tid >= off) ? partial[tid - off] : 0;
        __syncthreads();
        partial[tid] += tmp;
        __syncthreads();
    }
    int excl = partial[tid] - s;
#pragma unroll
    for (int q = 0; q < 16; q++) E[base + q] = excl + loc[q];
    if (tid == 255) E[4096] = partial[255];
}

// ---------------------------------------------------------------------------
// Kernel 4: per-group online-LSE, ONE WAVE PER GROUP (1024 blocks x 4 waves):
//  - E -> LDS once per block (one barrier)
//  - per-wave setup on lanes 0..2 at LDS latency (one barrier)
//  - branch-free two-pass sweep: pass A pipelined float4 loads + fmax chain
//    -> butterfly max; pass B reload (L1/L2-hot) + exp(val-M) -> butterfly add.
//    No inter-group barriers, no load->update dependency chains.
//  - per-block accumulation, one atomicAdd per block.
// ---------------------------------------------------------------------------
__global__ __launch_bounds__(256)
void group_kernel(const float* __restrict__ sim, const int* __restrict__ ex,
                  const int* __restrict__ E, float* __restrict__ out)
{
    const int tid  = threadIdx.x;
    const int wave = tid >> 6;
    const int lane = tid & 63;
    const int g    = blockIdx.x * 4 + wave;
    __shared__ int   sE[4097];
    __shared__ float posv[4][2];
    __shared__ int   pR[4][3], pCa[4][3], pCb[4][3], pX[4][3][4], nP[4];
    __shared__ float wgl[4];

    // ---- copy E -> LDS ----
    {
        const int b = tid * 16;
#pragma unroll
        for (int q = 0; q < 16; q += 4) {
            int4 v = *reinterpret_cast<const int4*>(E + b + q);
            sE[b+q] = v.x; sE[b+q+1] = v.y; sE[b+q+2] = v.z; sE[b+q+3] = v.w;
        }
        if (tid == 0) sE[4096] = E[4096];
    }
    __syncthreads();

    // ---- per-wave setup: lanes 0,1 -> positives; lane 2 -> negative pieces ----
    if (lane < 2) {
        int p = 2 * g + lane;
        int lo = 0, hi = N_ - 1;
        while (lo < hi) {
            int mid = (lo + hi + 1) >> 1;
            if (mid + sE[mid] <= p) lo = mid; else hi = mid - 1;
        }
        int r = lo;
        int q = p - (r + sE[r]);
        int pr = (r < B_) ? r + B_ : r - B_;
        int a0 = ex[2*r], a1 = ex[2*r+1];
        int p0 = pr, p1 = a0, p2 = a1;               // sort3 (sentinels last)
        if (p0 > p1) { int tm = p0; p0 = p1; p1 = tm; }
        if (p1 > p2) { int tm = p1; p1 = p2; p2 = tm; }
        if (p0 > p1) { int tm = p0; p0 = p1; p1 = tm; }
        int c = (q == 0) ? p0 : ((q == 1) ? p1 : p2);
        posv[wave][lane] = sim[(size_t)r * N_ + c];
    } else if (lane == 2) {
        long long s0 = (long long)NEGG * g;
        long long s1 = s0 + NEGG;
        int lo = 0, hi = N_ - 1;
        while (lo < hi) {
            int mid = (lo + hi + 1) >> 1;
            long long Q = 4094LL * mid - sE[mid];
            if (Q <= s0) lo = mid; else hi = mid - 1;
        }
        int np = 0;
        long long s = s0;
        int r = lo;
        while (s < s1 && np < 3) {
            long long Qr = 4094LL * r - sE[r];
            int er = sE[r+1] - sE[r];
            int nr = 4094 - er;
            long long ka = s - Qr;
            long long kb = s1 - Qr; if (kb > nr) kb = nr;
            int X[4];
            X[0] = (r < B_) ? r : r - B_;
            X[1] = (r < B_) ? r + B_ : r;
            X[2] = ex[2*r]; X[3] = ex[2*r+1];
            if (X[0] > X[1]) { int t = X[0]; X[0] = X[1]; X[1] = t; }
            if (X[2] > X[3]) { int t = X[2]; X[2] = X[3]; X[3] = t; }
            if (X[0] > X[2]) { int t = X[0]; X[0] = X[2]; X[2] = t; }
            if (X[1] > X[3]) { int t = X[1]; X[1] = X[3]; X[3] = t; }
            if (X[1] > X[2]) { int t = X[1]; X[1] = X[2]; X[2] = t; }
            int ca = (int)ka;
#pragma unroll
            for (int t = 0; t < 4; t++) if (X[t] <= ca) ca++;
            int cb = (int)kb - 1;
#pragma unroll
            for (int t = 0; t < 4; t++) if (X[t] <= cb) cb++;
            cb += 1;
            pR[wave][np] = r; pCa[wave][np] = ca; pCb[wave][np] = cb;
#pragma unroll
            for (int t = 0; t < 4; t++) pX[wave][np][t] = X[t];
            ++np;
            s += (kb - ka);
            r += 1;
        }
        nP[wave] = np;
    }
    __syncthreads();

    const int np = nP[wave];

    // ---- pass A: masked max (branch-free, pipelined loads) ----
    float lm = -3.0e38f;
    for (int pz = 0; pz < np; ++pz) {
        const int r = pR[wave][pz], ca = pCa[wave][pz], cb = pCb[wave][pz];
        const int X0 = pX[wave][pz][0], X1 = pX[wave][pz][1];
        const int X2 = pX[wave][pz][2], X3 = pX[wave][pz][3];
        const float* row = sim + (size_t)r * N_;
        const int base = ca & ~3;
        for (int c4 = base + lane * 4; c4 < cb; c4 += 256) {
            float4 v4 = *reinterpret_cast<const float4*>(row + c4);
            float vals[4] = { v4.x, v4.y, v4.z, v4.w };
#pragma unroll
            for (int u = 0; u < 4; ++u) {
                int c = c4 + u;
                bool keep = (c >= ca) & (c < cb) &
                            (c != X0) & (c != X1) & (c != X2) & (c != X3);
                lm = fmaxf(lm, keep ? vals[u] : -INFINITY);
            }
        }
    }
#pragma unroll
    for (int off = 32; off >= 1; off >>= 1)
        lm = fmaxf(lm, __shfl_xor(lm, off));

    // ---- pass B: sum of exp(val - M) (branch-free, pipelined reloads) ----
    float ls = 0.f;
    for (int pz = 0; pz < np; ++pz) {
        const int r = pR[wave][pz], ca = pCa[wave][pz], cb = pCb[wave][pz];
        const int X0 = pX[wave][pz][0], X1 = pX[wave][pz][1];
        const int X2 = pX[wave][pz][2], X3 = pX[wave][pz][3];
        const float* row = sim + (size_t)r * N_;
        const int base = ca & ~3;
        for (int c4 = base + lane * 4; c4 < cb; c4 += 256) {
            float4 v4 = *reinterpret_cast<const float4*>(row + c4);
            float vals[4] = { v4.x, v4.y, v4.z, v4.w };
#pragma unroll
            for (int u = 0; u < 4; ++u) {
                int c = c4 + u;
                bool keep = (c >= ca) & (c < cb) &
                            (c != X0) & (c != X1) & (c != X2) & (c != X3);
                ls += __expf((keep ? vals[u] : -INFINITY) - lm);  // exp(-inf)=0
            }
        }
    }
#pragma unroll
    for (int off = 32; off >= 1; off >>= 1)
        ls += __shfl_xor(ls, off);

    if (lane == 0) {
        float q0 = posv[wave][0], q1 = posv[wave][1];
        float nm = fmaxf(lm, fmaxf(q0, q1));
        float stot = ls * __expf(lm - nm) + __expf(q0 - nm) + __expf(q1 - nm);
        wgl[wave] = (nm + __logf(stot)) - q0;
    }
    __syncthreads();
    if (tid == 0) {
        float gl = wgl[0] + wgl[1] + wgl[2] + wgl[3];
        atomicAdd(out, gl * (1.0f / 4096.0f));
    }
}

// ---------------------------------------------------------------------------
extern "C" void kernel_launch(void* const* d_in, const int* in_sizes, int n_in,
                              void* d_out, int out_size, void* d_ws, size_t ws_size,
                              hipStream_t stream)
{
    const float* hi = (const float*)d_in[0];
    const float* hj = (const float*)d_in[1];
    char* ws = (char*)d_ws;
    size_t off = 0;
    float* sim = (float*)(ws + off); off += (size_t)N_ * N_ * sizeof(float);  // 64 MB
    f16*   Hh  = (f16*)(ws + off);   off += (size_t)N_ * D_ * sizeof(f16);    // 8 MB
    f16*   Hl  = (f16*)(ws + off);   off += (size_t)N_ * D_ * sizeof(f16);    // 8 MB
    int*   e   = (int*)(ws + off);   off += 4096 * sizeof(int);
    int*   ex  = (int*)(ws + off);   off += 8192 * sizeof(int);
    int*   E   = (int*)(ws + off);   off += 4100 * sizeof(int);

    split_kernel<<<(N_ * D_ / 4 + 255) / 256, 256, 0, stream>>>(hi, hj, Hh, Hl);
    const int nblocks = (N_ / 128) * (N_ / 128 - 1) / 2;   // 496 strict lower-tri
    gemm_kernel<<<nblocks, 256, 0, stream>>>(Hh, Hl, sim);
    topk_kernel<<<B_, 256, 0, stream>>>(sim, e, ex);
    scan_kernel<<<1, 256, 0, stream>>>(e, E, (float*)d_out);
    group_kernel<<<N_ / 4, 256, 0, stream>>>(sim, ex, E, (float*)d_out);
}

// Round 11
// 165.245 us; speedup vs baseline: 1.1110x; 1.0499x over previous
//
#include <hip/hip_runtime.h>
#include <math.h>

#define B_  2048
#define N_  4096
#define D_  1024
#define NEGG 4093   // negatives per group = N - 2 - K (K=1)

typedef _Float16 f16;
typedef unsigned long long u64;
typedef __attribute__((ext_vector_type(8))) _Float16 f16x8;
typedef __attribute__((ext_vector_type(4))) float     f32x4;

#define AS1 __attribute__((address_space(1)))
#define AS3 __attribute__((address_space(3)))

__device__ __forceinline__ void gload_lds16(const void* g, void* l) {
    __builtin_amdgcn_global_load_lds((const AS1 void*)g, (AS3 void*)l, 16, 0, 0);
}

// ---------------------------------------------------------------------------
// Kernel 0: split h=[h_i;h_j] (fp32) into fp16 hi/lo pair: h = hi + lo + O(2^-22)
// ---------------------------------------------------------------------------
struct alignas(8) h4 { f16 a, b, c, d; };

__global__ __launch_bounds__(256)
void split_kernel(const float* __restrict__ a, const float* __restrict__ b,
                  f16* __restrict__ ph, f16* __restrict__ pl)
{
    size_t t   = (size_t)blockIdx.x * 256 + threadIdx.x;
    size_t off = t * 4;                       // 4 floats per thread
    const size_t half = (size_t)B_ * D_;
    const float* src = (off < half) ? (a + off) : (b + (off - half));
    float4 v = *reinterpret_cast<const float4*>(src);
    f16 h0 = (f16)v.x, h1 = (f16)v.y, h2 = (f16)v.z, h3 = (f16)v.w;
    f16 l0 = (f16)(v.x - (float)h0);
    f16 l1 = (f16)(v.y - (float)h1);
    f16 l2 = (f16)(v.z - (float)h2);
    f16 l3 = (f16)(v.w - (float)h3);
    *reinterpret_cast<h4*>(ph + off) = {h0, h1, h2, h3};
    *reinterpret_cast<h4*>(pl + off) = {l0, l1, l2, l3};
}

// ---------------------------------------------------------------------------
// Kernel 1: sim = 2*(Hh Hh^T + Hh Hl^T + Hl Hh^T) via MFMA 16x16x32 f16.
// 496 strict-lower-tri 128x128 tiles; diag subtiles dealt s%31 across their
// 31 holder blocks; float4-transpose mirrors; XOR-swizzled LDS. (round-4 exact)
// ---------------------------------------------------------------------------
__global__ __launch_bounds__(256)
void gemm_kernel(const f16* __restrict__ Hh, const f16* __restrict__ Hl,
                 float* __restrict__ sim)
{
    __shared__ __align__(16) f16 lds[4][128 * 32];
    const int tid  = threadIdx.x;
    const int wave = tid >> 6;
    const int lane = tid & 63;

    int idx = blockIdx.x;
    int by = (int)((sqrtf(8.0f * (float)idx + 1.0f) + 1.0f) * 0.5f);
    while (by * (by - 1) / 2 > idx) --by;
    while ((by + 1) * by / 2 <= idx) ++by;
    int bx = idx - by * (by - 1) / 2;
    const int m0 = by * 128;
    const int n0 = bx * 128;

    int xs = -1, xpanel = 0, xb = 0;
    {
        int cnt = 0;
        for (int s = bx; s < 36; s += 31, ++cnt)
            if (cnt == wave) { xs = s; xpanel = 0; xb = by; }
        for (int s = by - 1; s < 36; s += 31, ++cnt)
            if (cnt == wave) { xs = s; xpanel = 2; xb = bx; }
    }
    int xmt = 0, xnt = 0;
    if (xs >= 0) {
        while ((xmt + 1) * (xmt + 2) / 2 <= xs) ++xmt;
        xnt = xs - xmt * (xmt + 1) / 2;
    }

    const int wm = (wave >> 1) * 64;
    const int wn = (wave & 1) * 64;
    const int l15  = lane & 15;
    const int quad = lane >> 4;

    f32x4 acc[4][4];
#pragma unroll
    for (int i = 0; i < 4; i++)
#pragma unroll
        for (int j = 0; j < 4; j++) { acc[i][j][0]=0.f; acc[i][j][1]=0.f; acc[i][j][2]=0.f; acc[i][j][3]=0.f; }
    f32x4 xacc; xacc[0]=0.f; xacc[1]=0.f; xacc[2]=0.f; xacc[3]=0.f;

    const int lr = lane >> 2;
    const int sw_st = (lr ^ (lr >> 2)) & 3;
    const f16* gsrc = ((wave & 1) ? Hl : Hh)
                    + (size_t)((wave & 2) ? n0 : m0) * D_
                    + (size_t)lr * D_ + (size_t)(((lane & 3) ^ sw_st) * 8);

    const int sw_rd = (l15 ^ (l15 >> 2)) & 3;

    for (int k0 = 0; k0 < D_; k0 += 32) {
#pragma unroll
        for (int s = 0; s < 8; ++s) {
            const f16* gp = gsrc + (size_t)(s * 16) * D_ + k0;
            gload_lds16(gp, &lds[wave][s * 512]);
        }
        __syncthreads();

        f16x8 ah[4], al[4], bh[4], bl[4];
        const int qc = ((quad ^ sw_rd) & 3) * 8;
#pragma unroll
        for (int mt = 0; mt < 4; ++mt) {
            int row = wm + mt * 16 + l15;
            ah[mt] = *reinterpret_cast<const f16x8*>(&lds[0][row * 32 + qc]);
            al[mt] = *reinterpret_cast<const f16x8*>(&lds[1][row * 32 + qc]);
        }
#pragma unroll
        for (int nt = 0; nt < 4; ++nt) {
            int row = wn + nt * 16 + l15;
            bh[nt] = *reinterpret_cast<const f16x8*>(&lds[2][row * 32 + qc]);
            bl[nt] = *reinterpret_cast<const f16x8*>(&lds[3][row * 32 + qc]);
        }
#pragma unroll
        for (int mt = 0; mt < 4; ++mt)
#pragma unroll
            for (int nt = 0; nt < 4; ++nt) {
                acc[mt][nt] = __builtin_amdgcn_mfma_f32_16x16x32_f16(ah[mt], bh[nt], acc[mt][nt], 0, 0, 0);
                acc[mt][nt] = __builtin_amdgcn_mfma_f32_16x16x32_f16(ah[mt], bl[nt], acc[mt][nt], 0, 0, 0);
                acc[mt][nt] = __builtin_amdgcn_mfma_f32_16x16x32_f16(al[mt], bh[nt], acc[mt][nt], 0, 0, 0);
            }
        if (xs >= 0) {
            f16x8 xah = *reinterpret_cast<const f16x8*>(&lds[xpanel    ][(xmt * 16 + l15) * 32 + qc]);
            f16x8 xal = *reinterpret_cast<const f16x8*>(&lds[xpanel + 1][(xmt * 16 + l15) * 32 + qc]);
            f16x8 xbh = *reinterpret_cast<const f16x8*>(&lds[xpanel    ][(xnt * 16 + l15) * 32 + qc]);
            f16x8 xbl = *reinterpret_cast<const f16x8*>(&lds[xpanel + 1][(xnt * 16 + l15) * 32 + qc]);
            xacc = __builtin_amdgcn_mfma_f32_16x16x32_f16(xah, xbh, xacc, 0, 0, 0);
            xacc = __builtin_amdgcn_mfma_f32_16x16x32_f16(xah, xbl, xacc, 0, 0, 0);
            xacc = __builtin_amdgcn_mfma_f32_16x16x32_f16(xal, xbh, xacc, 0, 0, 0);
        }
        __syncthreads();
    }

#pragma unroll
    for (int mt = 0; mt < 4; ++mt) {
        int r = m0 + wm + mt * 16 + quad * 4;
#pragma unroll
        for (int nt = 0; nt < 4; ++nt) {
            int c = n0 + wn + nt * 16 + l15;
#pragma unroll
            for (int reg = 0; reg < 4; ++reg)
                sim[(size_t)(r + reg) * N_ + c] = 2.0f * acc[mt][nt][reg];
        }
    }
#pragma unroll
    for (int mt = 0; mt < 4; ++mt) {
        int cb = m0 + wm + mt * 16 + quad * 4;
#pragma unroll
        for (int nt = 0; nt < 4; ++nt) {
            int rr = n0 + wn + nt * 16 + l15;
            float4 v = { 2.0f * acc[mt][nt][0], 2.0f * acc[mt][nt][1],
                         2.0f * acc[mt][nt][2], 2.0f * acc[mt][nt][3] };
            *reinterpret_cast<float4*>(&sim[(size_t)rr * N_ + cb]) = v;
        }
    }
    if (xs >= 0) {
        int rb = xb * 128 + xmt * 16 + quad * 4;
        int cc = xb * 128 + xnt * 16 + l15;
#pragma unroll
        for (int reg = 0; reg < 4; ++reg)
            sim[(size_t)(rb + reg) * N_ + cc] = 2.0f * xacc[reg];
        if (xmt != xnt) {
            int rr = xb * 128 + xnt * 16 + l15;
            int cb = xb * 128 + xmt * 16 + quad * 4;
            float4 v = { 2.0f * xacc[0], 2.0f * xacc[1], 2.0f * xacc[2], 2.0f * xacc[3] };
            *reinterpret_cast<float4*>(&sim[(size_t)rr * N_ + cb]) = v;
        }
    }
}

// ---------------------------------------------------------------------------
// Kernel 2: per-anchor top-4, BRANCH-FREE (round-8 exact: 2048 blocks).
// u64 key (mono(val)<<32)|(4095-j) == jax.lax.top_k stable order.
// ---------------------------------------------------------------------------
__device__ __forceinline__ u64 mkkey(float v, int j) {
    unsigned u = __float_as_uint(v);
    u = (u & 0x80000000u) ? ~u : (u | 0x80000000u);   // monotonic float map
    return ((u64)u << 32) | (unsigned)(4095 - j);
}

__device__ __forceinline__ void kins(u64& k0, u64& k1, u64& k2, u64& k3, u64 key) {
    u64 lo = key, t;
    t = (k0 > lo) ? k0 : lo; lo = (k0 > lo) ? lo : k0; k0 = t;
    t = (k1 > lo) ? k1 : lo; lo = (k1 > lo) ? lo : k1; k1 = t;
    t = (k2 > lo) ? k2 : lo; lo = (k2 > lo) ? lo : k2; k2 = t;
    k3 = (k3 > lo) ? k3 : lo;
}

__global__ __launch_bounds__(256)
void topk_kernel(const float* __restrict__ sim, int* __restrict__ e,
                 int* __restrict__ ex)
{
    const int i   = blockIdx.x;      // anchor
    const int tid = threadIdx.x;
    const float* rowA = sim + (size_t)i * N_ + B_;        // sim[i, B+j]
    const float* rowB = sim + (size_t)(B_ + i) * N_;      // sim[B+i, j]

    u64 k0 = 0, k1 = 0, k2 = 0, k3 = 0;   // 0 < every real key
#pragma unroll
    for (int it = 0; it < 4; ++it) {
        int base = tid * 4 + it * 1024;
        float4 v4 = (base < B_) ? *reinterpret_cast<const float4*>(rowA + base)
                                : *reinterpret_cast<const float4*>(rowB + (base - B_));
        float vals[4] = { v4.x, v4.y, v4.z, v4.w };
#pragma unroll
        for (int u = 0; u < 4; ++u)
            kins(k0, k1, k2, k3, mkkey(vals[u], base + u));
    }

    __shared__ u64 lk[1024];
    lk[tid * 4 + 0] = k0; lk[tid * 4 + 1] = k1;
    lk[tid * 4 + 2] = k2; lk[tid * 4 + 3] = k3;
    __syncthreads();

    if (tid < 64) {
#pragma unroll
        for (int w = 1; w < 4; ++w) {
            int th = tid + w * 64;
#pragma unroll
            for (int s = 0; s < 4; ++s)
                kins(k0, k1, k2, k3, lk[th * 4 + s]);
        }
        u64 M[4];
#pragma unroll
        for (int r = 0; r < 4; ++r) {
            u64 mx = k0;
#pragma unroll
            for (int off = 32; off >= 1; off >>= 1) {
                u64 o = __shfl_xor(mx, off);
                mx = (mx > o) ? mx : o;
            }
            M[r] = mx;
            if (k0 == mx) { k0 = k1; k1 = k2; k2 = k3; k3 = 0; }  // keys unique
        }
        if (tid == 0) {
            int topi[4];
#pragma unroll
            for (int r = 0; r < 4; ++r)
                topi[r] = 4095 - (int)(unsigned)(M[r] & 0xFFFFFFFFull);
            int exi[2] = {0x7fffffff, 0x7fffffff}; int ei = 0;
            int exb[2] = {0x7fffffff, 0x7fffffff}; int eb = 0;
            int taken = 0;
#pragma unroll
            for (int t = 0; t < 4; ++t) {
                if (taken >= 2) break;
                int idxj = topi[t];
                if (idxj == i || idxj == i + B_) continue;   // anchor pair: invalid
                ++taken;
                if (idxj < B_) exi[ei++] = B_ + idxj;        // row i, col B+idx
                else           exb[eb++] = idxj - B_;        // row B+i, col idx-B
            }
            if (ei == 2 && exi[0] > exi[1]) { int t = exi[0]; exi[0] = exi[1]; exi[1] = t; }
            if (eb == 2 && exb[0] > exb[1]) { int t = exb[0]; exb[0] = exb[1]; exb[1] = t; }
            e[i] = ei;        ex[2*i]        = exi[0]; ex[2*i+1]        = exi[1];
            e[B_ + i] = eb;   ex[2*(B_+i)]   = exb[0]; ex[2*(B_+i)+1]   = exb[1];
        }
    }
}

// ---------------------------------------------------------------------------
// Kernel 3: exclusive prefix sum E[r] of e[r]; also zeroes out[0].
// ---------------------------------------------------------------------------
__global__ __launch_bounds__(256)
void scan_kernel(const int* __restrict__ e, int* __restrict__ E,
                 float* __restrict__ out)
{
    __shared__ int partial[256];
    const int tid = threadIdx.x;
    if (tid == 0) out[0] = 0.0f;
    const int base = tid * 16;
    int loc[16];
    int s = 0;
#pragma unroll
    for (int q = 0; q < 16; q++) { loc[q] = s; s += e[base + q]; }
    partial[tid] = s;
    __syncthreads();
    for (int off = 1; off < 256; off <<= 1) {
        int tmp = (tid >= off) ? partial[tid - off] : 0;
        __syncthreads();
        partial[tid] += tmp;
        __syncthreads();
    }
    int excl = partial[tid] - s;
#pragma unroll
    for (int q = 0; q < 16; q++) E[base + q] = excl + loc[q];
    if (tid == 255) E[4096] = partial[255];
}

// ---------------------------------------------------------------------------
// Kernel 4: per-group LSE, one wave per group, SINGLE memory pass:
// negatives(g) = contiguous flat range [F0,F1) of sim minus <=12 point
// exclusions (pieces cover consecutive rows; gap elements between pieces are
// exactly the rows' excluded columns). Static 17-quad lane-strided sweep ->
// 68 register-resident masked values; butterfly max; 68 register exps;
// butterfly add. No online chain, no second memory pass.
// ---------------------------------------------------------------------------
__global__ __launch_bounds__(256)
void group_kernel(const float* __restrict__ sim, const int* __restrict__ ex,
                  const int* __restrict__ E, float* __restrict__ out)
{
    const int tid  = threadIdx.x;
    const int wave = tid >> 6;
    const int lane = tid & 63;
    const int g    = blockIdx.x * 4 + wave;
    __shared__ int   sE[4097];
    __shared__ float posv[4][2];
    __shared__ int   exf[4][12];
    __shared__ int   fF0[4], fF1[4];
    __shared__ float wgl[4];

    // ---- copy E -> LDS ----
    {
        const int b = tid * 16;
#pragma unroll
        for (int q = 0; q < 16; q += 4) {
            int4 v = *reinterpret_cast<const int4*>(E + b + q);
            sE[b+q] = v.x; sE[b+q+1] = v.y; sE[b+q+2] = v.z; sE[b+q+3] = v.w;
        }
        if (tid == 0) sE[4096] = E[4096];
    }
    __syncthreads();

    // ---- per-wave setup: lanes 0,1 -> positives; lane 2 -> flat range ----
    if (lane < 2) {
        int p = 2 * g + lane;
        int lo = 0, hi = N_ - 1;
        while (lo < hi) {
            int mid = (lo + hi + 1) >> 1;
            if (mid + sE[mid] <= p) lo = mid; else hi = mid - 1;
        }
        int r = lo;
        int q = p - (r + sE[r]);
        int pr = (r < B_) ? r + B_ : r - B_;
        int a0 = ex[2*r], a1 = ex[2*r+1];
        int p0 = pr, p1 = a0, p2 = a1;               // sort3 (sentinels last)
        if (p0 > p1) { int tm = p0; p0 = p1; p1 = tm; }
        if (p1 > p2) { int tm = p1; p1 = p2; p2 = tm; }
        if (p0 > p1) { int tm = p0; p0 = p1; p1 = tm; }
        int c = (q == 0) ? p0 : ((q == 1) ? p1 : p2);
        posv[wave][lane] = sim[(size_t)r * N_ + c];
    } else if (lane == 2) {
        long long s0 = (long long)NEGG * g;
        long long s1 = s0 + NEGG;
        int lo = 0, hi = N_ - 1;
        while (lo < hi) {
            int mid = (lo + hi + 1) >> 1;
            long long Q = 4094LL * mid - sE[mid];
            if (Q <= s0) lo = mid; else hi = mid - 1;
        }
        int lR[3], lCa[3], lCb[3], lX[3][4];
        int np = 0;
        long long s = s0;
        int r = lo;
        while (s < s1 && np < 3) {
            long long Qr = 4094LL * r - sE[r];
            int er = sE[r+1] - sE[r];
            int nr = 4094 - er;
            long long ka = s - Qr;
            long long kb = s1 - Qr; if (kb > nr) kb = nr;
            int X[4];
            X[0] = (r < B_) ? r : r - B_;
            X[1] = (r < B_) ? r + B_ : r;
            X[2] = ex[2*r]; X[3] = ex[2*r+1];
            if (X[0] > X[1]) { int t = X[0]; X[0] = X[1]; X[1] = t; }
            if (X[2] > X[3]) { int t = X[2]; X[2] = X[3]; X[3] = t; }
            if (X[0] > X[2]) { int t = X[0]; X[0] = X[2]; X[2] = t; }
            if (X[1] > X[3]) { int t = X[1]; X[1] = X[3]; X[3] = t; }
            if (X[1] > X[2]) { int t = X[1]; X[1] = X[2]; X[2] = t; }
            int ca = (int)ka;
#pragma unroll
            for (int t = 0; t < 4; t++) if (X[t] <= ca) ca++;
            int cb = (int)kb - 1;
#pragma unroll
            for (int t = 0; t < 4; t++) if (X[t] <= cb) cb++;
            cb += 1;
            lR[np] = r; lCa[np] = ca; lCb[np] = cb;
#pragma unroll
            for (int t = 0; t < 4; t++) lX[np][t] = X[t];
            ++np;
            s += (kb - ka);
            r += 1;
        }
        int F0 = lR[0] * N_ + lCa[0];
        int F1 = lR[np-1] * N_ + lCb[np-1];
        fF0[wave] = F0; fF1[wave] = F1;
#pragma unroll
        for (int pz = 0; pz < 3; ++pz)
#pragma unroll
            for (int t = 0; t < 4; ++t) {
                int fx = -1;
                if (pz < np && lX[pz][t] < N_) {
                    int cand = lR[pz] * N_ + lX[pz][t];
                    if (cand >= F0 && cand < F1) fx = cand;
                }
                exf[wave][pz * 4 + t] = fx;
            }
    }
    __syncthreads();

    const int F0 = fF0[wave], F1 = fF1[wave];
    int exr[12];
#pragma unroll
    for (int t = 0; t < 12; ++t) exr[t] = exf[wave][t];
    const int base4 = F0 & ~3;

    // ---- single pass: load + mask into registers, track max ----
    float v[17][4];
    float lm = -3.0e38f;
#pragma unroll
    for (int it = 0; it < 17; ++it) {
        int c4 = base4 + (it * 64 + lane) * 4;
        int c4s = (c4 > N_ * N_ - 4) ? (N_ * N_ - 4) : c4;
        float4 q = *reinterpret_cast<const float4*>(sim + c4s);
        float vals[4] = { q.x, q.y, q.z, q.w };
#pragma unroll
        for (int u = 0; u < 4; ++u) {
            int f = c4 + u;
            bool keep = (f >= F0) & (f < F1);
#pragma unroll
            for (int t = 0; t < 12; ++t) keep &= (f != exr[t]);
            float val = keep ? vals[u] : -INFINITY;
            v[it][u] = val;
            lm = fmaxf(lm, val);
        }
    }
#pragma unroll
    for (int off = 32; off >= 1; off >>= 1)
        lm = fmaxf(lm, __shfl_xor(lm, off));

    float ls = 0.f;
#pragma unroll
    for (int it = 0; it < 17; ++it)
#pragma unroll
        for (int u = 0; u < 4; ++u)
            ls += __expf(v[it][u] - lm);          // exp(-inf)=0 for masked
#pragma unroll
    for (int off = 32; off >= 1; off >>= 1)
        ls += __shfl_xor(ls, off);

    if (lane == 0) {
        float q0 = posv[wave][0], q1 = posv[wave][1];
        float nm = fmaxf(lm, fmaxf(q0, q1));
        float stot = ls * __expf(lm - nm) + __expf(q0 - nm) + __expf(q1 - nm);
        wgl[wave] = (nm + __logf(stot)) - q0;
    }
    __syncthreads();
    if (tid == 0) {
        float gl = wgl[0] + wgl[1] + wgl[2] + wgl[3];
        atomicAdd(out, gl * (1.0f / 4096.0f));
    }
}

// ---------------------------------------------------------------------------
extern "C" void kernel_launch(void* const* d_in, const int* in_sizes, int n_in,
                              void* d_out, int out_size, void* d_ws, size_t ws_size,
                              hipStream_t stream)
{
    const float* hi = (const float*)d_in[0];
    const float* hj = (const float*)d_in[1];
    char* ws = (char*)d_ws;
    size_t off = 0;
    float* sim = (float*)(ws + off); off += (size_t)N_ * N_ * sizeof(float);  // 64 MB
    f16*   Hh  = (f16*)(ws + off);   off += (size_t)N_ * D_ * sizeof(f16);    // 8 MB
    f16*   Hl  = (f16*)(ws + off);   off += (size_t)N_ * D_ * sizeof(f16);    // 8 MB
    int*   e   = (int*)(ws + off);   off += 4096 * sizeof(int);
    int*   ex  = (int*)(ws + off);   off += 8192 * sizeof(int);
    int*   E   = (int*)(ws + off);   off += 4100 * sizeof(int);

    split_kernel<<<(N_ * D_ / 4 + 255) / 256, 256, 0, stream>>>(hi, hj, Hh, Hl);
    const int nblocks = (N_ / 128) * (N_ / 128 - 1) / 2;   // 496 strict lower-tri
    gemm_kernel<<<nblocks, 256, 0, stream>>>(Hh, Hl, sim);
    topk_kernel<<<B_, 256, 0, stream>>>(sim, e, ex);
    scan_kernel<<<1, 256, 0, stream>>>(e, E, (float*)d_out);
    group_kernel<<<N_ / 4, 256, 0, stream>>>(sim, ex, E, (float*)d_out);
}

// Round 12
// 164.183 us; speedup vs baseline: 1.1182x; 1.0065x over previous
//
#include <hip/hip_runtime.h>
#include <math.h>

#define B_  2048
#define N_  4096
#define D_  1024
#define NEGG 4093   // negatives per group = N - 2 - K (K=1)

typedef _Float16 f16;
typedef unsigned long long u64;
typedef __attribute__((ext_vector_type(8))) _Float16 f16x8;
typedef __attribute__((ext_vector_type(4))) float     f32x4;

#define AS1 __attribute__((address_space(1)))
#define AS3 __attribute__((address_space(3)))

__device__ __forceinline__ void gload_lds16(const void* g, void* l) {
    __builtin_amdgcn_global_load_lds((const AS1 void*)g, (AS3 void*)l, 16, 0, 0);
}

// ---------------------------------------------------------------------------
// Kernel 0: split h=[h_i;h_j] (fp32) into fp16 hi/lo pair; block 0 zeroes
// out[0] (group's atomic target runs two kernels later, same stream).
// ---------------------------------------------------------------------------
struct alignas(8) h4 { f16 a, b, c, d; };

__global__ __launch_bounds__(256)
void split_kernel(const float* __restrict__ a, const float* __restrict__ b,
                  f16* __restrict__ ph, f16* __restrict__ pl,
                  float* __restrict__ out)
{
    if (blockIdx.x == 0 && threadIdx.x == 0) out[0] = 0.0f;
    size_t t   = (size_t)blockIdx.x * 256 + threadIdx.x;
    size_t off = t * 4;                       // 4 floats per thread
    const size_t half = (size_t)B_ * D_;
    const float* src = (off < half) ? (a + off) : (b + (off - half));
    float4 v = *reinterpret_cast<const float4*>(src);
    f16 h0 = (f16)v.x, h1 = (f16)v.y, h2 = (f16)v.z, h3 = (f16)v.w;
    f16 l0 = (f16)(v.x - (float)h0);
    f16 l1 = (f16)(v.y - (float)h1);
    f16 l2 = (f16)(v.z - (float)h2);
    f16 l3 = (f16)(v.w - (float)h3);
    *reinterpret_cast<h4*>(ph + off) = {h0, h1, h2, h3};
    *reinterpret_cast<h4*>(pl + off) = {l0, l1, l2, l3};
}

// ---------------------------------------------------------------------------
// Kernel 1: sim = 2*(Hh Hh^T + Hh Hl^T + Hl Hh^T) via MFMA 16x16x32 f16.
// 496 strict-lower-tri 128x128 tiles; diag subtiles dealt s%31 across their
// 31 holder blocks; float4-transpose mirrors; XOR-swizzled LDS. (round-4 exact)
// ---------------------------------------------------------------------------
__global__ __launch_bounds__(256)
void gemm_kernel(const f16* __restrict__ Hh, const f16* __restrict__ Hl,
                 float* __restrict__ sim)
{
    __shared__ __align__(16) f16 lds[4][128 * 32];
    const int tid  = threadIdx.x;
    const int wave = tid >> 6;
    const int lane = tid & 63;

    int idx = blockIdx.x;
    int by = (int)((sqrtf(8.0f * (float)idx + 1.0f) + 1.0f) * 0.5f);
    while (by * (by - 1) / 2 > idx) --by;
    while ((by + 1) * by / 2 <= idx) ++by;
    int bx = idx - by * (by - 1) / 2;
    const int m0 = by * 128;
    const int n0 = bx * 128;

    int xs = -1, xpanel = 0, xb = 0;
    {
        int cnt = 0;
        for (int s = bx; s < 36; s += 31, ++cnt)
            if (cnt == wave) { xs = s; xpanel = 0; xb = by; }
        for (int s = by - 1; s < 36; s += 31, ++cnt)
            if (cnt == wave) { xs = s; xpanel = 2; xb = bx; }
    }
    int xmt = 0, xnt = 0;
    if (xs >= 0) {
        while ((xmt + 1) * (xmt + 2) / 2 <= xs) ++xmt;
        xnt = xs - xmt * (xmt + 1) / 2;
    }

    const int wm = (wave >> 1) * 64;
    const int wn = (wave & 1) * 64;
    const int l15  = lane & 15;
    const int quad = lane >> 4;

    f32x4 acc[4][4];
#pragma unroll
    for (int i = 0; i < 4; i++)
#pragma unroll
        for (int j = 0; j < 4; j++) { acc[i][j][0]=0.f; acc[i][j][1]=0.f; acc[i][j][2]=0.f; acc[i][j][3]=0.f; }
    f32x4 xacc; xacc[0]=0.f; xacc[1]=0.f; xacc[2]=0.f; xacc[3]=0.f;

    const int lr = lane >> 2;
    const int sw_st = (lr ^ (lr >> 2)) & 3;
    const f16* gsrc = ((wave & 1) ? Hl : Hh)
                    + (size_t)((wave & 2) ? n0 : m0) * D_
                    + (size_t)lr * D_ + (size_t)(((lane & 3) ^ sw_st) * 8);

    const int sw_rd = (l15 ^ (l15 >> 2)) & 3;

    for (int k0 = 0; k0 < D_; k0 += 32) {
#pragma unroll
        for (int s = 0; s < 8; ++s) {
            const f16* gp = gsrc + (size_t)(s * 16) * D_ + k0;
            gload_lds16(gp, &lds[wave][s * 512]);
        }
        __syncthreads();

        f16x8 ah[4], al[4], bh[4], bl[4];
        const int qc = ((quad ^ sw_rd) & 3) * 8;
#pragma unroll
        for (int mt = 0; mt < 4; ++mt) {
            int row = wm + mt * 16 + l15;
            ah[mt] = *reinterpret_cast<const f16x8*>(&lds[0][row * 32 + qc]);
            al[mt] = *reinterpret_cast<const f16x8*>(&lds[1][row * 32 + qc]);
        }
#pragma unroll
        for (int nt = 0; nt < 4; ++nt) {
            int row = wn + nt * 16 + l15;
            bh[nt] = *reinterpret_cast<const f16x8*>(&lds[2][row * 32 + qc]);
            bl[nt] = *reinterpret_cast<const f16x8*>(&lds[3][row * 32 + qc]);
        }
#pragma unroll
        for (int mt = 0; mt < 4; ++mt)
#pragma unroll
            for (int nt = 0; nt < 4; ++nt) {
                acc[mt][nt] = __builtin_amdgcn_mfma_f32_16x16x32_f16(ah[mt], bh[nt], acc[mt][nt], 0, 0, 0);
                acc[mt][nt] = __builtin_amdgcn_mfma_f32_16x16x32_f16(ah[mt], bl[nt], acc[mt][nt], 0, 0, 0);
                acc[mt][nt] = __builtin_amdgcn_mfma_f32_16x16x32_f16(al[mt], bh[nt], acc[mt][nt], 0, 0, 0);
            }
        if (xs >= 0) {
            f16x8 xah = *reinterpret_cast<const f16x8*>(&lds[xpanel    ][(xmt * 16 + l15) * 32 + qc]);
            f16x8 xal = *reinterpret_cast<const f16x8*>(&lds[xpanel + 1][(xmt * 16 + l15) * 32 + qc]);
            f16x8 xbh = *reinterpret_cast<const f16x8*>(&lds[xpanel    ][(xnt * 16 + l15) * 32 + qc]);
            f16x8 xbl = *reinterpret_cast<const f16x8*>(&lds[xpanel + 1][(xnt * 16 + l15) * 32 + qc]);
            xacc = __builtin_amdgcn_mfma_f32_16x16x32_f16(xah, xbh, xacc, 0, 0, 0);
            xacc = __builtin_amdgcn_mfma_f32_16x16x32_f16(xah, xbl, xacc, 0, 0, 0);
            xacc = __builtin_amdgcn_mfma_f32_16x16x32_f16(xal, xbh, xacc, 0, 0, 0);
        }
        __syncthreads();
    }

#pragma unroll
    for (int mt = 0; mt < 4; ++mt) {
        int r = m0 + wm + mt * 16 + quad * 4;
#pragma unroll
        for (int nt = 0; nt < 4; ++nt) {
            int c = n0 + wn + nt * 16 + l15;
#pragma unroll
            for (int reg = 0; reg < 4; ++reg)
                sim[(size_t)(r + reg) * N_ + c] = 2.0f * acc[mt][nt][reg];
        }
    }
#pragma unroll
    for (int mt = 0; mt < 4; ++mt) {
        int cb = m0 + wm + mt * 16 + quad * 4;
#pragma unroll
        for (int nt = 0; nt < 4; ++nt) {
            int rr = n0 + wn + nt * 16 + l15;
            float4 v = { 2.0f * acc[mt][nt][0], 2.0f * acc[mt][nt][1],
                         2.0f * acc[mt][nt][2], 2.0f * acc[mt][nt][3] };
            *reinterpret_cast<float4*>(&sim[(size_t)rr * N_ + cb]) = v;
        }
    }
    if (xs >= 0) {
        int rb = xb * 128 + xmt * 16 + quad * 4;
        int cc = xb * 128 + xnt * 16 + l15;
#pragma unroll
        for (int reg = 0; reg < 4; ++reg)
            sim[(size_t)(rb + reg) * N_ + cc] = 2.0f * xacc[reg];
        if (xmt != xnt) {
            int rr = xb * 128 + xnt * 16 + l15;
            int cb = xb * 128 + xmt * 16 + quad * 4;
            float4 v = { 2.0f * xacc[0], 2.0f * xacc[1], 2.0f * xacc[2], 2.0f * xacc[3] };
            *reinterpret_cast<float4*>(&sim[(size_t)rr * N_ + cb]) = v;
        }
    }
}

// ---------------------------------------------------------------------------
// Kernel 2: per-anchor top-4, BRANCH-FREE (round-8 exact: 2048 blocks).
// u64 key (mono(val)<<32)|(4095-j) == jax.lax.top_k stable order.
// ---------------------------------------------------------------------------
__device__ __forceinline__ u64 mkkey(float v, int j) {
    unsigned u = __float_as_uint(v);
    u = (u & 0x80000000u) ? ~u : (u | 0x80000000u);   // monotonic float map
    return ((u64)u << 32) | (unsigned)(4095 - j);
}

__device__ __forceinline__ void kins(u64& k0, u64& k1, u64& k2, u64& k3, u64 key) {
    u64 lo = key, t;
    t = (k0 > lo) ? k0 : lo; lo = (k0 > lo) ? lo : k0; k0 = t;
    t = (k1 > lo) ? k1 : lo; lo = (k1 > lo) ? lo : k1; k1 = t;
    t = (k2 > lo) ? k2 : lo; lo = (k2 > lo) ? lo : k2; k2 = t;
    k3 = (k3 > lo) ? k3 : lo;
}

__global__ __launch_bounds__(256)
void topk_kernel(const float* __restrict__ sim, int* __restrict__ e,
                 int* __restrict__ ex)
{
    const int i   = blockIdx.x;      // anchor
    const int tid = threadIdx.x;
    const float* rowA = sim + (size_t)i * N_ + B_;        // sim[i, B+j]
    const float* rowB = sim + (size_t)(B_ + i) * N_;      // sim[B+i, j]

    u64 k0 = 0, k1 = 0, k2 = 0, k3 = 0;   // 0 < every real key
#pragma unroll
    for (int it = 0; it < 4; ++it) {
        int base = tid * 4 + it * 1024;
        float4 v4 = (base < B_) ? *reinterpret_cast<const float4*>(rowA + base)
                                : *reinterpret_cast<const float4*>(rowB + (base - B_));
        float vals[4] = { v4.x, v4.y, v4.z, v4.w };
#pragma unroll
        for (int u = 0; u < 4; ++u)
            kins(k0, k1, k2, k3, mkkey(vals[u], base + u));
    }

    __shared__ u64 lk[1024];
    lk[tid * 4 + 0] = k0; lk[tid * 4 + 1] = k1;
    lk[tid * 4 + 2] = k2; lk[tid * 4 + 3] = k3;
    __syncthreads();

    if (tid < 64) {
#pragma unroll
        for (int w = 1; w < 4; ++w) {
            int th = tid + w * 64;
#pragma unroll
            for (int s = 0; s < 4; ++s)
                kins(k0, k1, k2, k3, lk[th * 4 + s]);
        }
        u64 M[4];
#pragma unroll
        for (int r = 0; r < 4; ++r) {
            u64 mx = k0;
#pragma unroll
            for (int off = 32; off >= 1; off >>= 1) {
                u64 o = __shfl_xor(mx, off);
                mx = (mx > o) ? mx : o;
            }
            M[r] = mx;
            if (k0 == mx) { k0 = k1; k1 = k2; k2 = k3; k3 = 0; }  // keys unique
        }
        if (tid == 0) {
            int topi[4];
#pragma unroll
            for (int r = 0; r < 4; ++r)
                topi[r] = 4095 - (int)(unsigned)(M[r] & 0xFFFFFFFFull);
            int exi[2] = {0x7fffffff, 0x7fffffff}; int ei = 0;
            int exb[2] = {0x7fffffff, 0x7fffffff}; int eb = 0;
            int taken = 0;
#pragma unroll
            for (int t = 0; t < 4; ++t) {
                if (taken >= 2) break;
                int idxj = topi[t];
                if (idxj == i || idxj == i + B_) continue;   // anchor pair: invalid
                ++taken;
                if (idxj < B_) exi[ei++] = B_ + idxj;        // row i, col B+idx
                else           exb[eb++] = idxj - B_;        // row B+i, col idx-B
            }
            if (ei == 2 && exi[0] > exi[1]) { int t = exi[0]; exi[0] = exi[1]; exi[1] = t; }
            if (eb == 2 && exb[0] > exb[1]) { int t = exb[0]; exb[0] = exb[1]; exb[1] = t; }
            e[i] = ei;        ex[2*i]        = exi[0]; ex[2*i+1]        = exi[1];
            e[B_ + i] = eb;   ex[2*(B_+i)]   = exb[0]; ex[2*(B_+i)+1]   = exb[1];
        }
    }
}

// ---------------------------------------------------------------------------
// Kernel 3: per-group LSE, one wave per group, single memory pass; the E
// prefix scan is computed IN-BLOCK from e (16 KB read — same bytes the old
// E->LDS copy cost; scan kernel + one launch boundary eliminated).
// negatives(g) = contiguous flat range [F0,F1) minus <=12 point exclusions;
// static 17-quad lane-strided sweep -> 68 register-resident masked values;
// butterfly max; 68 register exps; butterfly add; one atomicAdd per block.
// ---------------------------------------------------------------------------
__global__ __launch_bounds__(256)
void group_kernel(const float* __restrict__ sim, const int* __restrict__ e,
                  const int* __restrict__ ex, float* __restrict__ out)
{
    const int tid  = threadIdx.x;
    const int wave = tid >> 6;
    const int lane = tid & 63;
    const int g    = blockIdx.x * 4 + wave;
    __shared__ int   sE[4097];
    __shared__ int   partial[256];
    __shared__ float posv[4][2];
    __shared__ int   exf[4][12];
    __shared__ int   fF0[4], fF1[4];
    __shared__ float wgl[4];

    // ---- in-block exclusive prefix scan of e -> sE (round-7-proven code) ----
    {
        const int base0 = tid * 16;
        int loc[16];
        int s = 0;
#pragma unroll
        for (int q = 0; q < 16; q += 4) {
            int4 ev = *reinterpret_cast<const int4*>(e + base0 + q);
            loc[q+0] = s; s += ev.x;
            loc[q+1] = s; s += ev.y;
            loc[q+2] = s; s += ev.z;
            loc[q+3] = s; s += ev.w;
        }
        partial[tid] = s;
        __syncthreads();
        for (int off = 1; off < 256; off <<= 1) {
            int tmp = (tid >= off) ? partial[tid - off] : 0;
            __syncthreads();
            partial[tid] += tmp;
            __syncthreads();
        }
        int excl = partial[tid] - s;
#pragma unroll
        for (int q = 0; q < 16; q++) sE[base0 + q] = excl + loc[q];
        if (tid == 255) sE[4096] = partial[255];
    }
    __syncthreads();

    // ---- per-wave setup: lanes 0,1 -> positives; lane 2 -> flat range ----
    if (lane < 2) {
        int p = 2 * g + lane;
        int lo = 0, hi = N_ - 1;
        while (lo < hi) {
            int mid = (lo + hi + 1) >> 1;
            if (mid + sE[mid] <= p) lo = mid; else hi = mid - 1;
        }
        int r = lo;
        int q = p - (r + sE[r]);
        int pr = (r < B_) ? r + B_ : r - B_;
        int a0 = ex[2*r], a1 = ex[2*r+1];
        int p0 = pr, p1 = a0, p2 = a1;               // sort3 (sentinels last)
        if (p0 > p1) { int tm = p0; p0 = p1; p1 = tm; }
        if (p1 > p2) { int tm = p1; p1 = p2; p2 = tm; }
        if (p0 > p1) { int tm = p0; p0 = p1; p1 = tm; }
        int c = (q == 0) ? p0 : ((q == 1) ? p1 : p2);
        posv[wave][lane] = sim[(size_t)r * N_ + c];
    } else if (lane == 2) {
        long long s0 = (long long)NEGG * g;
        long long s1 = s0 + NEGG;
        int lo = 0, hi = N_ - 1;
        while (lo < hi) {
            int mid = (lo + hi + 1) >> 1;
            long long Q = 4094LL * mid - sE[mid];
            if (Q <= s0) lo = mid; else hi = mid - 1;
        }
        int lR[3], lCa[3], lCb[3], lX[3][4];
        int np = 0;
        long long s = s0;
        int r = lo;
        while (s < s1 && np < 3) {
            long long Qr = 4094LL * r - sE[r];
            int er = sE[r+1] - sE[r];
            int nr = 4094 - er;
            long long ka = s - Qr;
            long long kb = s1 - Qr; if (kb > nr) kb = nr;
            int X[4];
            X[0] = (r < B_) ? r : r - B_;
            X[1] = (r < B_) ? r + B_ : r;
            X[2] = ex[2*r]; X[3] = ex[2*r+1];
            if (X[0] > X[1]) { int t = X[0]; X[0] = X[1]; X[1] = t; }
            if (X[2] > X[3]) { int t = X[2]; X[2] = X[3]; X[3] = t; }
            if (X[0] > X[2]) { int t = X[0]; X[0] = X[2]; X[2] = t; }
            if (X[1] > X[3]) { int t = X[1]; X[1] = X[3]; X[3] = t; }
            if (X[1] > X[2]) { int t = X[1]; X[1] = X[2]; X[2] = t; }
            int ca = (int)ka;
#pragma unroll
            for (int t = 0; t < 4; t++) if (X[t] <= ca) ca++;
            int cb = (int)kb - 1;
#pragma unroll
            for (int t = 0; t < 4; t++) if (X[t] <= cb) cb++;
            cb += 1;
            lR[np] = r; lCa[np] = ca; lCb[np] = cb;
#pragma unroll
            for (int t = 0; t < 4; t++) lX[np][t] = X[t];
            ++np;
            s += (kb - ka);
            r += 1;
        }
        int F0 = lR[0] * N_ + lCa[0];
        int F1 = lR[np-1] * N_ + lCb[np-1];
        fF0[wave] = F0; fF1[wave] = F1;
#pragma unroll
        for (int pz = 0; pz < 3; ++pz)
#pragma unroll
            for (int t = 0; t < 4; ++t) {
                int fx = -1;
                if (pz < np && lX[pz][t] < N_) {
                    int cand = lR[pz] * N_ + lX[pz][t];
                    if (cand >= F0 && cand < F1) fx = cand;
                }
                exf[wave][pz * 4 + t] = fx;
            }
    }
    __syncthreads();

    const int F0 = fF0[wave], F1 = fF1[wave];
    int exr[12];
#pragma unroll
    for (int t = 0; t < 12; ++t) exr[t] = exf[wave][t];
    const int base4 = F0 & ~3;

    // ---- single pass: load + mask into registers, track max ----
    float v[17][4];
    float lm = -3.0e38f;
#pragma unroll
    for (int it = 0; it < 17; ++it) {
        int c4 = base4 + (it * 64 + lane) * 4;
        int c4s = (c4 > N_ * N_ - 4) ? (N_ * N_ - 4) : c4;
        float4 q = *reinterpret_cast<const float4*>(sim + c4s);
        float vals[4] = { q.x, q.y, q.z, q.w };
#pragma unroll
        for (int u = 0; u < 4; ++u) {
            int f = c4 + u;
            bool keep = (f >= F0) & (f < F1);
#pragma unroll
            for (int t = 0; t < 12; ++t) keep &= (f != exr[t]);
            float val = keep ? vals[u] : -INFINITY;
            v[it][u] = val;
            lm = fmaxf(lm, val);
        }
    }
#pragma unroll
    for (int off = 32; off >= 1; off >>= 1)
        lm = fmaxf(lm, __shfl_xor(lm, off));

    float ls = 0.f;
#pragma unroll
    for (int it = 0; it < 17; ++it)
#pragma unroll
        for (int u = 0; u < 4; ++u)
            ls += __expf(v[it][u] - lm);          // exp(-inf)=0 for masked
#pragma unroll
    for (int off = 32; off >= 1; off >>= 1)
        ls += __shfl_xor(ls, off);

    if (lane == 0) {
        float q0 = posv[wave][0], q1 = posv[wave][1];
        float nm = fmaxf(lm, fmaxf(q0, q1));
        float stot = ls * __expf(lm - nm) + __expf(q0 - nm) + __expf(q1 - nm);
        wgl[wave] = (nm + __logf(stot)) - q0;
    }
    __syncthreads();
    if (tid == 0) {
        float gl = wgl[0] + wgl[1] + wgl[2] + wgl[3];
        atomicAdd(out, gl * (1.0f / 4096.0f));
    }
}

// ---------------------------------------------------------------------------
extern "C" void kernel_launch(void* const* d_in, const int* in_sizes, int n_in,
                              void* d_out, int out_size, void* d_ws, size_t ws_size,
                              hipStream_t stream)
{
    const float* hi = (const float*)d_in[0];
    const float* hj = (const float*)d_in[1];
    char* ws = (char*)d_ws;
    size_t off = 0;
    float* sim = (float*)(ws + off); off += (size_t)N_ * N_ * sizeof(float);  // 64 MB
    f16*   Hh  = (f16*)(ws + off);   off += (size_t)N_ * D_ * sizeof(f16);    // 8 MB
    f16*   Hl  = (f16*)(ws + off);   off += (size_t)N_ * D_ * sizeof(f16);    // 8 MB
    int*   e   = (int*)(ws + off);   off += 4096 * sizeof(int);
    int*   ex  = (int*)(ws + off);   off += 8192 * sizeof(int);

    split_kernel<<<(N_ * D_ / 4 + 255) / 256, 256, 0, stream>>>(hi, hj, Hh, Hl, (float*)d_out);
    const int nblocks = (N_ / 128) * (N_ / 128 - 1) / 2;   // 496 strict lower-tri
    gemm_kernel<<<nblocks, 256, 0, stream>>>(Hh, Hl, sim);
    topk_kernel<<<B_, 256, 0, stream>>>(sim, e, ex);
    group_kernel<<<N_ / 4, 256, 0, stream>>>(sim, e, ex, (float*)d_out);
}

// Round 13
// 160.477 us; speedup vs baseline: 1.1440x; 1.0231x over previous
//
#include <hip/hip_runtime.h>
#include <math.h>

#define B_  2048
#define N_  4096
#define D_  1024
#define NEGG 4093   // negatives per group = N - 2 - K (K=1)

typedef _Float16 f16;
typedef unsigned long long u64;
typedef __attribute__((ext_vector_type(8))) _Float16 f16x8;
typedef __attribute__((ext_vector_type(4))) float     f32x4;

#define AS1 __attribute__((address_space(1)))
#define AS3 __attribute__((address_space(3)))

__device__ __forceinline__ void gload_lds16(const void* g, void* l) {
    __builtin_amdgcn_global_load_lds((const AS1 void*)g, (AS3 void*)l, 16, 0, 0);
}

// ---------------------------------------------------------------------------
// Kernel 0: split h=[h_i;h_j] (fp32) into fp16 hi/lo pair; block 0 zeroes
// out[0] (group's atomic target runs two kernels later, same stream).
// ---------------------------------------------------------------------------
struct alignas(8) h4 { f16 a, b, c, d; };

__global__ __launch_bounds__(256)
void split_kernel(const float* __restrict__ a, const float* __restrict__ b,
                  f16* __restrict__ ph, f16* __restrict__ pl,
                  float* __restrict__ out)
{
    if (blockIdx.x == 0 && threadIdx.x == 0) out[0] = 0.0f;
    size_t t   = (size_t)blockIdx.x * 256 + threadIdx.x;
    size_t off = t * 4;                       // 4 floats per thread
    const size_t half = (size_t)B_ * D_;
    const float* src = (off < half) ? (a + off) : (b + (off - half));
    float4 v = *reinterpret_cast<const float4*>(src);
    f16 h0 = (f16)v.x, h1 = (f16)v.y, h2 = (f16)v.z, h3 = (f16)v.w;
    f16 l0 = (f16)(v.x - (float)h0);
    f16 l1 = (f16)(v.y - (float)h1);
    f16 l2 = (f16)(v.z - (float)h2);
    f16 l3 = (f16)(v.w - (float)h3);
    *reinterpret_cast<h4*>(ph + off) = {h0, h1, h2, h3};
    *reinterpret_cast<h4*>(pl + off) = {l0, l1, l2, l3};
}

// ---------------------------------------------------------------------------
// Kernel 1: sim = 2*(Hh Hh^T + Hh Hl^T + Hl Hh^T) via MFMA 16x16x32 f16.
// 496 strict-lower-tri 128x128 tiles; diag subtiles dealt s%31; mirrors.
// BK=64: 64 KB LDS (still 2 blocks/CU — grid-limited at 1.94, so m132's
// occupancy failure-mode doesn't apply) -> HALF the barriers (16 K-iters).
// Swizzle generalized to 8 chunks: phys_chunk = c ^ (row&7) -> 2 lanes per
// bank group on ds_read_b128 = conflict-free (m136).
// ---------------------------------------------------------------------------
__global__ __launch_bounds__(256)
void gemm_kernel(const f16* __restrict__ Hh, const f16* __restrict__ Hl,
                 float* __restrict__ sim)
{
    __shared__ __align__(16) f16 lds[4][128 * 64];   // 4 x 16 KB = 64 KB
    const int tid  = threadIdx.x;
    const int wave = tid >> 6;
    const int lane = tid & 63;

    int idx = blockIdx.x;
    int by = (int)((sqrtf(8.0f * (float)idx + 1.0f) + 1.0f) * 0.5f);
    while (by * (by - 1) / 2 > idx) --by;
    while ((by + 1) * by / 2 <= idx) ++by;
    int bx = idx - by * (by - 1) / 2;
    const int m0 = by * 128;
    const int n0 = bx * 128;

    int xs = -1, xpanel = 0, xb = 0;
    {
        int cnt = 0;
        for (int s = bx; s < 36; s += 31, ++cnt)
            if (cnt == wave) { xs = s; xpanel = 0; xb = by; }
        for (int s = by - 1; s < 36; s += 31, ++cnt)
            if (cnt == wave) { xs = s; xpanel = 2; xb = bx; }
    }
    int xmt = 0, xnt = 0;
    if (xs >= 0) {
        while ((xmt + 1) * (xmt + 2) / 2 <= xs) ++xmt;
        xnt = xs - xmt * (xmt + 1) / 2;
    }

    const int wm = (wave >> 1) * 64;
    const int wn = (wave & 1) * 64;
    const int l15  = lane & 15;
    const int quad = lane >> 4;

    f32x4 acc[4][4];
#pragma unroll
    for (int i = 0; i < 4; i++)
#pragma unroll
        for (int j = 0; j < 4; j++) { acc[i][j][0]=0.f; acc[i][j][1]=0.f; acc[i][j][2]=0.f; acc[i][j][3]=0.f; }
    f32x4 xacc; xacc[0]=0.f; xacc[1]=0.f; xacc[2]=0.f; xacc[3]=0.f;

    // staging (BK=64): lane -> row lane>>3 (8 rows/instr), chunk lane&7;
    // fetch swizzled global chunk so LDS[r][c] = A[r][(c ^ (r&7))*8 ..]
    const int lr8 = lane >> 3;
    const f16* gsrc = ((wave & 1) ? Hl : Hh)
                    + (size_t)((wave & 2) ? n0 : m0) * D_
                    + (size_t)lr8 * D_ + (size_t)(((lane & 7) ^ lr8) * 8);

    const int r7 = l15 & 7;                     // row&7 for all fragment rows

    for (int k0 = 0; k0 < D_; k0 += 64) {
#pragma unroll
        for (int s = 0; s < 16; ++s) {
            const f16* gp = gsrc + (size_t)(s * 8) * D_ + k0;
            gload_lds16(gp, &lds[wave][s * 512]);   // 8 rows x 64 f16 per instr
        }
        __syncthreads();

#pragma unroll
        for (int ks = 0; ks < 2; ++ks) {
            const int qc = (((ks << 2) | quad) ^ r7) * 8;
            f16x8 ah[4], al[4], bh[4], bl[4];
#pragma unroll
            for (int mt = 0; mt < 4; ++mt) {
                int row = wm + mt * 16 + l15;
                ah[mt] = *reinterpret_cast<const f16x8*>(&lds[0][row * 64 + qc]);
                al[mt] = *reinterpret_cast<const f16x8*>(&lds[1][row * 64 + qc]);
            }
#pragma unroll
            for (int nt = 0; nt < 4; ++nt) {
                int row = wn + nt * 16 + l15;
                bh[nt] = *reinterpret_cast<const f16x8*>(&lds[2][row * 64 + qc]);
                bl[nt] = *reinterpret_cast<const f16x8*>(&lds[3][row * 64 + qc]);
            }
#pragma unroll
            for (int mt = 0; mt < 4; ++mt)
#pragma unroll
                for (int nt = 0; nt < 4; ++nt) {
                    acc[mt][nt] = __builtin_amdgcn_mfma_f32_16x16x32_f16(ah[mt], bh[nt], acc[mt][nt], 0, 0, 0);
                    acc[mt][nt] = __builtin_amdgcn_mfma_f32_16x16x32_f16(ah[mt], bl[nt], acc[mt][nt], 0, 0, 0);
                    acc[mt][nt] = __builtin_amdgcn_mfma_f32_16x16x32_f16(al[mt], bh[nt], acc[mt][nt], 0, 0, 0);
                }
            if (xs >= 0) {
                f16x8 xah = *reinterpret_cast<const f16x8*>(&lds[xpanel    ][(xmt * 16 + l15) * 64 + qc]);
                f16x8 xal = *reinterpret_cast<const f16x8*>(&lds[xpanel + 1][(xmt * 16 + l15) * 64 + qc]);
                f16x8 xbh = *reinterpret_cast<const f16x8*>(&lds[xpanel    ][(xnt * 16 + l15) * 64 + qc]);
                f16x8 xbl = *reinterpret_cast<const f16x8*>(&lds[xpanel + 1][(xnt * 16 + l15) * 64 + qc]);
                xacc = __builtin_amdgcn_mfma_f32_16x16x32_f16(xah, xbh, xacc, 0, 0, 0);
                xacc = __builtin_amdgcn_mfma_f32_16x16x32_f16(xah, xbl, xacc, 0, 0, 0);
                xacc = __builtin_amdgcn_mfma_f32_16x16x32_f16(xal, xbh, xacc, 0, 0, 0);
            }
        }
        __syncthreads();
    }

#pragma unroll
    for (int mt = 0; mt < 4; ++mt) {
        int r = m0 + wm + mt * 16 + quad * 4;
#pragma unroll
        for (int nt = 0; nt < 4; ++nt) {
            int c = n0 + wn + nt * 16 + l15;
#pragma unroll
            for (int reg = 0; reg < 4; ++reg)
                sim[(size_t)(r + reg) * N_ + c] = 2.0f * acc[mt][nt][reg];
        }
    }
#pragma unroll
    for (int mt = 0; mt < 4; ++mt) {
        int cb = m0 + wm + mt * 16 + quad * 4;
#pragma unroll
        for (int nt = 0; nt < 4; ++nt) {
            int rr = n0 + wn + nt * 16 + l15;
            float4 v = { 2.0f * acc[mt][nt][0], 2.0f * acc[mt][nt][1],
                         2.0f * acc[mt][nt][2], 2.0f * acc[mt][nt][3] };
            *reinterpret_cast<float4*>(&sim[(size_t)rr * N_ + cb]) = v;
        }
    }
    if (xs >= 0) {
        int rb = xb * 128 + xmt * 16 + quad * 4;
        int cc = xb * 128 + xnt * 16 + l15;
#pragma unroll
        for (int reg = 0; reg < 4; ++reg)
            sim[(size_t)(rb + reg) * N_ + cc] = 2.0f * xacc[reg];
        if (xmt != xnt) {
            int rr = xb * 128 + xnt * 16 + l15;
            int cb = xb * 128 + xmt * 16 + quad * 4;
            float4 v = { 2.0f * xacc[0], 2.0f * xacc[1], 2.0f * xacc[2], 2.0f * xacc[3] };
            *reinterpret_cast<float4*>(&sim[(size_t)rr * N_ + cb]) = v;
        }
    }
}

// ---------------------------------------------------------------------------
// Kernel 2: per-anchor top-4, BRANCH-FREE (round-8 exact: 2048 blocks).
// u64 key (mono(val)<<32)|(4095-j) == jax.lax.top_k stable order.
// ---------------------------------------------------------------------------
__device__ __forceinline__ u64 mkkey(float v, int j) {
    unsigned u = __float_as_uint(v);
    u = (u & 0x80000000u) ? ~u : (u | 0x80000000u);   // monotonic float map
    return ((u64)u << 32) | (unsigned)(4095 - j);
}

__device__ __forceinline__ void kins(u64& k0, u64& k1, u64& k2, u64& k3, u64 key) {
    u64 lo = key, t;
    t = (k0 > lo) ? k0 : lo; lo = (k0 > lo) ? lo : k0; k0 = t;
    t = (k1 > lo) ? k1 : lo; lo = (k1 > lo) ? lo : k1; k1 = t;
    t = (k2 > lo) ? k2 : lo; lo = (k2 > lo) ? lo : k2; k2 = t;
    k3 = (k3 > lo) ? k3 : lo;
}

__global__ __launch_bounds__(256)
void topk_kernel(const float* __restrict__ sim, int* __restrict__ e,
                 int* __restrict__ ex)
{
    const int i   = blockIdx.x;      // anchor
    const int tid = threadIdx.x;
    const float* rowA = sim + (size_t)i * N_ + B_;        // sim[i, B+j]
    const float* rowB = sim + (size_t)(B_ + i) * N_;      // sim[B+i, j]

    u64 k0 = 0, k1 = 0, k2 = 0, k3 = 0;   // 0 < every real key
#pragma unroll
    for (int it = 0; it < 4; ++it) {
        int base = tid * 4 + it * 1024;
        float4 v4 = (base < B_) ? *reinterpret_cast<const float4*>(rowA + base)
                                : *reinterpret_cast<const float4*>(rowB + (base - B_));
        float vals[4] = { v4.x, v4.y, v4.z, v4.w };
#pragma unroll
        for (int u = 0; u < 4; ++u)
            kins(k0, k1, k2, k3, mkkey(vals[u], base + u));
    }

    __shared__ u64 lk[1024];
    lk[tid * 4 + 0] = k0; lk[tid * 4 + 1] = k1;
    lk[tid * 4 + 2] = k2; lk[tid * 4 + 3] = k3;
    __syncthreads();

    if (tid < 64) {
#pragma unroll
        for (int w = 1; w < 4; ++w) {
            int th = tid + w * 64;
#pragma unroll
            for (int s = 0; s < 4; ++s)
                kins(k0, k1, k2, k3, lk[th * 4 + s]);
        }
        u64 M[4];
#pragma unroll
        for (int r = 0; r < 4; ++r) {
            u64 mx = k0;
#pragma unroll
            for (int off = 32; off >= 1; off >>= 1) {
                u64 o = __shfl_xor(mx, off);
                mx = (mx > o) ? mx : o;
            }
            M[r] = mx;
            if (k0 == mx) { k0 = k1; k1 = k2; k2 = k3; k3 = 0; }  // keys unique
        }
        if (tid == 0) {
            int topi[4];
#pragma unroll
            for (int r = 0; r < 4; ++r)
                topi[r] = 4095 - (int)(unsigned)(M[r] & 0xFFFFFFFFull);
            int exi[2] = {0x7fffffff, 0x7fffffff}; int ei = 0;
            int exb[2] = {0x7fffffff, 0x7fffffff}; int eb = 0;
            int taken = 0;
#pragma unroll
            for (int t = 0; t < 4; ++t) {
                if (taken >= 2) break;
                int idxj = topi[t];
                if (idxj == i || idxj == i + B_) continue;   // anchor pair: invalid
                ++taken;
                if (idxj < B_) exi[ei++] = B_ + idxj;        // row i, col B+idx
                else           exb[eb++] = idxj - B_;        // row B+i, col idx-B
            }
            if (ei == 2 && exi[0] > exi[1]) { int t = exi[0]; exi[0] = exi[1]; exi[1] = t; }
            if (eb == 2 && exb[0] > exb[1]) { int t = exb[0]; exb[0] = exb[1]; exb[1] = t; }
            e[i] = ei;        ex[2*i]        = exi[0]; ex[2*i+1]        = exi[1];
            e[B_ + i] = eb;   ex[2*(B_+i)]   = exb[0]; ex[2*(B_+i)+1]   = exb[1];
        }
    }
}

// ---------------------------------------------------------------------------
// Kernel 3: per-group LSE, one wave per group, single memory pass; E scan
// computed in-block from e. negatives(g) = flat range [F0,F1) minus <=12
// point exclusions; static 17-quad sweep -> 68 register-resident values;
// butterfly max; register exps; butterfly add; one atomicAdd per block.
// ---------------------------------------------------------------------------
__global__ __launch_bounds__(256)
void group_kernel(const float* __restrict__ sim, const int* __restrict__ e,
                  const int* __restrict__ ex, float* __restrict__ out)
{
    const int tid  = threadIdx.x;
    const int wave = tid >> 6;
    const int lane = tid & 63;
    const int g    = blockIdx.x * 4 + wave;
    __shared__ int   sE[4097];
    __shared__ int   partial[256];
    __shared__ float posv[4][2];
    __shared__ int   exf[4][12];
    __shared__ int   fF0[4], fF1[4];
    __shared__ float wgl[4];

    // ---- in-block exclusive prefix scan of e -> sE ----
    {
        const int base0 = tid * 16;
        int loc[16];
        int s = 0;
#pragma unroll
        for (int q = 0; q < 16; q += 4) {
            int4 ev = *reinterpret_cast<const int4*>(e + base0 + q);
            loc[q+0] = s; s += ev.x;
            loc[q+1] = s; s += ev.y;
            loc[q+2] = s; s += ev.z;
            loc[q+3] = s; s += ev.w;
        }
        partial[tid] = s;
        __syncthreads();
        for (int off = 1; off < 256; off <<= 1) {
            int tmp = (tid >= off) ? partial[tid - off] : 0;
            __syncthreads();
            partial[tid] += tmp;
            __syncthreads();
        }
        int excl = partial[tid] - s;
#pragma unroll
        for (int q = 0; q < 16; q++) sE[base0 + q] = excl + loc[q];
        if (tid == 255) sE[4096] = partial[255];
    }
    __syncthreads();

    // ---- per-wave setup: lanes 0,1 -> positives; lane 2 -> flat range ----
    if (lane < 2) {
        int p = 2 * g + lane;
        int lo = 0, hi = N_ - 1;
        while (lo < hi) {
            int mid = (lo + hi + 1) >> 1;
            if (mid + sE[mid] <= p) lo = mid; else hi = mid - 1;
        }
        int r = lo;
        int q = p - (r + sE[r]);
        int pr = (r < B_) ? r + B_ : r - B_;
        int a0 = ex[2*r], a1 = ex[2*r+1];
        int p0 = pr, p1 = a0, p2 = a1;               // sort3 (sentinels last)
        if (p0 > p1) { int tm = p0; p0 = p1; p1 = tm; }
        if (p1 > p2) { int tm = p1; p1 = p2; p2 = tm; }
        if (p0 > p1) { int tm = p0; p0 = p1; p1 = tm; }
        int c = (q == 0) ? p0 : ((q == 1) ? p1 : p2);
        posv[wave][lane] = sim[(size_t)r * N_ + c];
    } else if (lane == 2) {
        long long s0 = (long long)NEGG * g;
        long long s1 = s0 + NEGG;
        int lo = 0, hi = N_ - 1;
        while (lo < hi) {
            int mid = (lo + hi + 1) >> 1;
            long long Q = 4094LL * mid - sE[mid];
            if (Q <= s0) lo = mid; else hi = mid - 1;
        }
        int lR[3], lCa[3], lCb[3], lX[3][4];
        int np = 0;
        long long s = s0;
        int r = lo;
        while (s < s1 && np < 3) {
            long long Qr = 4094LL * r - sE[r];
            int er = sE[r+1] - sE[r];
            int nr = 4094 - er;
            long long ka = s - Qr;
            long long kb = s1 - Qr; if (kb > nr) kb = nr;
            int X[4];
            X[0] = (r < B_) ? r : r - B_;
            X[1] = (r < B_) ? r + B_ : r;
            X[2] = ex[2*r]; X[3] = ex[2*r+1];
            if (X[0] > X[1]) { int t = X[0]; X[0] = X[1]; X[1] = t; }
            if (X[2] > X[3]) { int t = X[2]; X[2] = X[3]; X[3] = t; }
            if (X[0] > X[2]) { int t = X[0]; X[0] = X[2]; X[2] = t; }
            if (X[1] > X[3]) { int t = X[1]; X[1] = X[3]; X[3] = t; }
            if (X[1] > X[2]) { int t = X[1]; X[1] = X[2]; X[2] = t; }
            int ca = (int)ka;
#pragma unroll
            for (int t = 0; t < 4; t++) if (X[t] <= ca) ca++;
            int cb = (int)kb - 1;
#pragma unroll
            for (int t = 0; t < 4; t++) if (X[t] <= cb) cb++;
            cb += 1;
            lR[np] = r; lCa[np] = ca; lCb[np] = cb;
#pragma unroll
            for (int t = 0; t < 4; t++) lX[np][t] = X[t];
            ++np;
            s += (kb - ka);
            r += 1;
        }
        int F0 = lR[0] * N_ + lCa[0];
        int F1 = lR[np-1] * N_ + lCb[np-1];
        fF0[wave] = F0; fF1[wave] = F1;
#pragma unroll
        for (int pz = 0; pz < 3; ++pz)
#pragma unroll
            for (int t = 0; t < 4; ++t) {
                int fx = -1;
                if (pz < np && lX[pz][t] < N_) {
                    int cand = lR[pz] * N_ + lX[pz][t];
                    if (cand >= F0 && cand < F1) fx = cand;
                }
                exf[wave][pz * 4 + t] = fx;
            }
    }
    __syncthreads();

    const int F0 = fF0[wave], F1 = fF1[wave];
    int exr[12];
#pragma unroll
    for (int t = 0; t < 12; ++t) exr[t] = exf[wave][t];
    const int base4 = F0 & ~3;

    // ---- single pass: load + mask into registers, track max ----
    float v[17][4];
    float lm = -3.0e38f;
#pragma unroll
    for (int it = 0; it < 17; ++it) {
        int c4 = base4 + (it * 64 + lane) * 4;
        int c4s = (c4 > N_ * N_ - 4) ? (N_ * N_ - 4) : c4;
        float4 q = *reinterpret_cast<const float4*>(sim + c4s);
        float vals[4] = { q.x, q.y, q.z, q.w };
#pragma unroll
        for (int u = 0; u < 4; ++u) {
            int f = c4 + u;
            bool keep = (f >= F0) & (f < F1);
#pragma unroll
            for (int t = 0; t < 12; ++t) keep &= (f != exr[t]);
            float val = keep ? vals[u] : -INFINITY;
            v[it][u] = val;
            lm = fmaxf(lm, val);
        }
    }
#pragma unroll
    for (int off = 32; off >= 1; off >>= 1)
        lm = fmaxf(lm, __shfl_xor(lm, off));

    float ls = 0.f;
#pragma unroll
    for (int it = 0; it < 17; ++it)
#pragma unroll
        for (int u = 0; u < 4; ++u)
            ls += __expf(v[it][u] - lm);          // exp(-inf)=0 for masked
#pragma unroll
    for (int off = 32; off >= 1; off >>= 1)
        ls += __shfl_xor(ls, off);

    if (lane == 0) {
        float q0 = posv[wave][0], q1 = posv[wave][1];
        float nm = fmaxf(lm, fmaxf(q0, q1));
        float stot = ls * __expf(lm - nm) + __expf(q0 - nm) + __expf(q1 - nm);
        wgl[wave] = (nm + __logf(stot)) - q0;
    }
    __syncthreads();
    if (tid == 0) {
        float gl = wgl[0] + wgl[1] + wgl[2] + wgl[3];
        atomicAdd(out, gl * (1.0f / 4096.0f));
    }
}

// ---------------------------------------------------------------------------
extern "C" void kernel_launch(void* const* d_in, const int* in_sizes, int n_in,
                              void* d_out, int out_size, void* d_ws, size_t ws_size,
                              hipStream_t stream)
{
    const float* hi = (const float*)d_in[0];
    const float* hj = (const float*)d_in[1];
    char* ws = (char*)d_ws;
    size_t off = 0;
    float* sim = (float*)(ws + off); off += (size_t)N_ * N_ * sizeof(float);  // 64 MB
    f16*   Hh  = (f16*)(ws + off);   off += (size_t)N_ * D_ * sizeof(f16);    // 8 MB
    f16*   Hl  = (f16*)(ws + off);   off += (size_t)N_ * D_ * sizeof(f16);    // 8 MB
    int*   e   = (int*)(ws + off);   off += 4096 * sizeof(int);
    int*   ex  = (int*)(ws + off);   off += 8192 * sizeof(int);

    split_kernel<<<(N_ * D_ / 4 + 255) / 256, 256, 0, stream>>>(hi, hj, Hh, Hl, (float*)d_out);
    const int nblocks = (N_ / 128) * (N_ / 128 - 1) / 2;   // 496 strict lower-tri
    gemm_kernel<<<nblocks, 256, 0, stream>>>(Hh, Hl, sim);
    topk_kernel<<<B_, 256, 0, stream>>>(sim, e, ex);
    group_kernel<<<N_ / 4, 256, 0, stream>>>(sim, e, ex, (float*)d_out);
}